// Round 10
// baseline (469.663 us; speedup 1.0000x reference)
//
#include <hip/hip_runtime.h>
#include <math.h>

// ---------------------------------------------------------------------------
// EdgeClassifier: 2x SAGEConv(mean) -> per-node MLP -> edge scorer
//  * layer-1 agg: mean commutes with projection -> aggregate raw nf (4-dim),
//    fused with h1 compute; quarter-wave (16 lanes) per node, DPP all-reduce
//  * CSR: R4-proven build: rank_k (atomic returning rank) + scan +
//    atomic-free fill2_k scatter into slot4 {src, eid, dst, packbf(ef4)}
//    + eb[pos] = {packbf(ef0,ef1), packbf(ef2,ef3)}  (ef pre-packed to bf16
//    in SLOT order -- removes edge_k's random-eid ef gather, ~100+MB of
//    line overfetch -> 13MB sequential stream; bit-identical numerics since
//    R8's edge_k only ever used bf16(ef) as the MFMA B-frag).
//  * gatherh1/aggh1f: 1-deep slot-index prefetch (R7-verified neutral/+)
//  * node_mlp_mfma_k: MFMA (16x16x32 bf16) node MLP; weights pre-split
//    hi/lo bf16 (prep_w_k); swapped operands -> direct ushort4 ST stores.
//  * edge_k: EXACT R8 MFMA form (449us E2E best; VGPR 84, WRITE 52MB),
//    only the ef source swapped for slot-ordered eb + slot4.w.
//    EVIDENCE LEDGER: R4 scalar (VALU 86%) = R8 MFMA (VALU 57%) = R9
//    deep-pipeline (occ 20%) = 131-133us, FETCH invariant ~322MB ->
//    edge_k is FETCH-bound; only byte reduction can move it.
//    R9 deep pipeline RETIRED (null). Packed-f2 RETIRED (R3/R5 spills).
//    R6 atomic-claim fill RETIRED (140us, WRITE 101MB).
//    TRIPWIRES: WRITE>60MB = spill -> revert; absmax != 4.882812e-4 ->
//    eb-path bug -> revert.
// ---------------------------------------------------------------------------

typedef __attribute__((ext_vector_type(8))) short bf16x8;
typedef __attribute__((ext_vector_type(4))) float f32x4;

__device__ __forceinline__ float fast_tanh(float x) {
    x = fminf(fmaxf(x, -15.f), 15.f);
    float e2 = __expf(2.f * x);
    return (e2 - 1.f) * __builtin_amdgcn_rcpf(e2 + 1.f);
}
__device__ __forceinline__ float fast_sigmoid(float x) {
    x = fminf(fmaxf(x, -60.f), 60.f);
    return __builtin_amdgcn_rcpf(1.f + __expf(-x));
}
__device__ __forceinline__ unsigned short f2bf(float f) {   // RNE
    unsigned u = __float_as_uint(f);
    u = u + 0x7FFFu + ((u >> 16) & 1u);
    return (unsigned short)(u >> 16);
}
__device__ __forceinline__ unsigned pack2bf(float lo, float hi) {
    return ((unsigned)f2bf(hi) << 16) | (unsigned)f2bf(lo);
}
__device__ __forceinline__ float bflo(unsigned u) { return __uint_as_float(u << 16); }
__device__ __forceinline__ float bfhi(unsigned u) { return __uint_as_float(u & 0xFFFF0000u); }
__device__ __forceinline__ float bf2f(unsigned short h) {
    return __uint_as_float((unsigned)h << 16);
}

__device__ __forceinline__ f32x4 mfma16(uint4 a, uint4 b, f32x4 c) {
    return __builtin_amdgcn_mfma_f32_16x16x32_bf16(
        __builtin_bit_cast(bf16x8, a), __builtin_bit_cast(bf16x8, b), c, 0, 0, 0);
}

// 16-lane all-reduce sum, pure DPP (no LDS/DS); reduces within 16-lane rows
__device__ __forceinline__ float dpp_sum16(float x) {
    int t;
    t = __builtin_amdgcn_update_dpp(0, __float_as_int(x), 0xB1, 0xF, 0xF, true);  // quad_perm(1,0,3,2)
    x += __int_as_float(t);
    t = __builtin_amdgcn_update_dpp(0, __float_as_int(x), 0x4E, 0xF, 0xF, true);  // quad_perm(2,3,0,1)
    x += __int_as_float(t);
    t = __builtin_amdgcn_update_dpp(0, __float_as_int(x), 0x141, 0xF, 0xF, true); // row_half_mirror
    x += __int_as_float(t);
    t = __builtin_amdgcn_update_dpp(0, __float_as_int(x), 0x140, 0xF, 0xF, true); // row_mirror
    x += __int_as_float(t);
    return x;
}

// rank[e] = arrival index among edges sharing dst; deg accumulates counts
__global__ void rank_k(const int* __restrict__ dst, int* __restrict__ deg,
                       int* __restrict__ rank, int E) {
    int e = blockIdx.x * blockDim.x + threadIdx.x;
    if (e < E) rank[e] = atomicAdd(&deg[dst[e]], 1);
}

__global__ void scan1_k(const int* __restrict__ deg, int* __restrict__ off,
                        int* __restrict__ bsum, int N) {
    __shared__ int tmp[256];
    int i = blockIdx.x * 256 + threadIdx.x;
    int v = (i < N) ? deg[i] : 0;
    tmp[threadIdx.x] = v;
    __syncthreads();
#pragma unroll
    for (int s = 1; s < 256; s <<= 1) {
        int t = (threadIdx.x >= s) ? tmp[threadIdx.x - s] : 0;
        __syncthreads();
        tmp[threadIdx.x] += t;
        __syncthreads();
    }
    if (i < N) off[i] = tmp[threadIdx.x] - v;
    if (threadIdx.x == 255) bsum[blockIdx.x] = tmp[255];
}

__global__ void scan2_k(int* __restrict__ bsum, int nb) {
    __shared__ int tmp[512];
    int i = threadIdx.x;
    int v = (i < nb) ? bsum[i] : 0;
    tmp[i] = v;
    __syncthreads();
#pragma unroll
    for (int s = 1; s < 512; s <<= 1) {
        int t = (i >= s) ? tmp[i - s] : 0;
        __syncthreads();
        tmp[i] += t;
        __syncthreads();
    }
    if (i < nb) bsum[i] = tmp[i] - v;
}

__global__ void scan3_k(int* __restrict__ off, const int* __restrict__ bsum,
                        int N, int E) {
    int i = blockIdx.x * 256 + threadIdx.x;
    if (i < N) off[i] += bsum[blockIdx.x];
    if (i == 0) off[N] = E;
}

// atomic-free CSR fill: slot4 {src, eid, dst, packbf(ef4)} + eb bf16 pairs.
// ef read is sequential by e; eb/slot4 scatters are bucket-local (benign).
__global__ void fill2_k(const int* __restrict__ src, const int* __restrict__ dst,
                        const int* __restrict__ off, const int* __restrict__ rank,
                        const float* __restrict__ ef,
                        int4* __restrict__ slot4, uint2* __restrict__ eb, int E) {
    int e = blockIdx.x * blockDim.x + threadIdx.x;
    if (e >= E) return;
    int d = dst[e];
    int pos = off[d] + rank[e];
    const float* ep = ef + (size_t)e * 5;
    float e0 = ep[0], e1 = ep[1], e2 = ep[2], e3 = ep[3], e4 = ep[4];
    slot4[pos] = make_int4(src[e], e, d, (int)pack2bf(e4, 0.f));
    eb[pos] = make_uint2(pack2bf(e0, e1), pack2bf(e2, e3));
}

// ---------------------------------------------------------------------------
// Weight prep (runs once): MFMA fragment-layout hi/lo bf16 copies, plus
// edge A-frag table efragT[8][64]: tiles 0..3 = We1 rows 128..132 (t path),
// tiles 4..7 = Wl1 rows 128..132 (u path). kq==0 lanes carry hi bf16 at
// k=0..4; kq==1 lanes carry lo residual at k=8..12 (hi/lo-in-K trick:
// B duplicates ef in both k ranges, one MFMA sums both products).
// ---------------------------------------------------------------------------
__global__ void prep_w_k(const float* __restrict__ W2s, const float* __restrict__ W2n,
                         const float* __restrict__ Wnp, const float* __restrict__ We1,
                         const float* __restrict__ Wl1, uint4* __restrict__ w2sF,
                         uint4* __restrict__ w2nF, uint4* __restrict__ wnpF,
                         uint4* __restrict__ wbigF, uint4* __restrict__ efragT) {
    const int b = blockIdx.x, t = threadIdx.x;
    if (b < 3) {
        const float* W = (b == 0) ? W2s : (b == 1) ? W2n : Wnp;
        uint4* out = (b == 0) ? w2sF : (b == 1) ? w2nF : wnpF;
        for (int u = t; u < 2 * 4 * 64; u += 256) {
            int l = u & 63, nt = (u >> 6) & 3, ks = u >> 8;
            int m = nt * 16 + (l & 15), kb = ks * 32 + (l >> 4) * 8;
            unsigned hi[4], lo[4];
#pragma unroll
            for (int jp = 0; jp < 4; ++jp) {
                float v0 = W[(kb + 2 * jp) * 64 + m];
                float v1 = W[(kb + 2 * jp + 1) * 64 + m];
                unsigned short h0 = f2bf(v0), h1 = f2bf(v1);
                unsigned short q0 = f2bf(v0 - bf2f(h0)), q1 = f2bf(v1 - bf2f(h1));
                hi[jp] = ((unsigned)h1 << 16) | h0;
                lo[jp] = ((unsigned)q1 << 16) | q0;
            }
            out[u * 2]     = make_uint4(hi[0], hi[1], hi[2], hi[3]);
            out[u * 2 + 1] = make_uint4(lo[0], lo[1], lo[2], lo[3]);
        }
    } else if (b == 3) {
        for (int u = t; u < 2 * 16 * 64; u += 256) {
            int l = u & 63, nt = (u >> 6) & 15, ks = u >> 10;
            int m = nt * 16 + (l & 15), kb = ks * 32 + (l >> 4) * 8;
            int half = m >> 7, cc = m & 127, jj = cc >> 1, p = cc & 1;
            const float* W = p ? Wl1 : We1;
            unsigned hi[4], lo[4];
#pragma unroll
            for (int jp = 0; jp < 4; ++jp) {
                float v0 = W[(half * 64 + kb + 2 * jp) * 64 + jj];
                float v1 = W[(half * 64 + kb + 2 * jp + 1) * 64 + jj];
                unsigned short h0 = f2bf(v0), h1 = f2bf(v1);
                unsigned short q0 = f2bf(v0 - bf2f(h0)), q1 = f2bf(v1 - bf2f(h1));
                hi[jp] = ((unsigned)h1 << 16) | h0;
                lo[jp] = ((unsigned)q1 << 16) | q0;
            }
            wbigF[u * 2]     = make_uint4(hi[0], hi[1], hi[2], hi[3]);
            wbigF[u * 2 + 1] = make_uint4(lo[0], lo[1], lo[2], lo[3]);
        }
    } else {
        for (int u = t; u < 8 * 64; u += 256) {
            int l = u & 63, tile = u >> 6;
            int kq = l >> 4, m16 = l & 15;
            const float* W = (tile < 4) ? We1 : Wl1;
            int c = (tile & 3) * 16 + m16;
            unsigned uu0 = 0u, uu1 = 0u, uu2 = 0u;
            if (kq < 2) {
                float v[5];
#pragma unroll
                for (int j = 0; j < 5; ++j) {
                    float wv = W[(128 + j) * 64 + c];
                    unsigned short h = f2bf(wv);
                    v[j] = (kq == 0) ? bf2f(h) : (wv - bf2f(h));
                }
                uu0 = pack2bf(v[0], v[1]);
                uu1 = pack2bf(v[2], v[3]);
                uu2 = pack2bf(v[4], 0.f);
            }
            efragT[tile * 64 + l] = make_uint4(uu0, uu1, uu2, 0u);
        }
    }
}

// quarter-wave (16 lanes) per node, 16 nodes/block: aggnf = mean of
// nf[neighbors] (stride-16 gather + DPP-16 all-reduce, 1-deep index
// prefetch), then lane q computes h1 cols 4q..4q+3, packed bf16.
__global__ __launch_bounds__(256, 8)
void aggh1f_k(const int* __restrict__ off, const int4* __restrict__ slot4,
              const float* __restrict__ nf,
              const float* __restrict__ W1s, const float* __restrict__ W1n,
              const float* __restrict__ b1, unsigned* __restrict__ h1b, int N) {
    int n = blockIdx.x * 16 + (threadIdx.x >> 4);
    if (n >= N) return;
    int q = threadIdx.x & 15;
    int s0 = off[n], s1 = off[n + 1];
    const float4* nf4 = (const float4*)nf;
    float4 a = {0.f, 0.f, 0.f, 0.f};
    int i = s0 + q;
    int nx = (i < s1) ? slot4[i].x : 0;
    for (; i < s1; ) {
        int cur = nx;
        int in = i + 16;
        if (in < s1) nx = slot4[in].x;       // prefetch next index
        float4 r = nf4[(unsigned)cur];
        a.x += r.x; a.y += r.y; a.z += r.z; a.w += r.w;
        i = in;
    }
    a.x = dpp_sum16(a.x);
    a.y = dpp_sum16(a.y);
    a.z = dpp_sum16(a.z);
    a.w = dpp_sum16(a.w);
    float invd = 1.f / fmaxf((float)(s1 - s0), 1.f);
    a.x *= invd; a.y *= invd; a.z *= invd; a.w *= invd;
    float4 r = nf4[(unsigned)n];
    const int j0 = q << 2;
    float4 acc = *(const float4*)&b1[j0];
#pragma unroll
    for (int k = 0; k < 4; ++k) {
        float rk = (k == 0) ? r.x : (k == 1) ? r.y : (k == 2) ? r.z : r.w;
        float ak = (k == 0) ? a.x : (k == 1) ? a.y : (k == 2) ? a.z : a.w;
        float4 ws = *(const float4*)&W1s[k * 64 + j0];
        float4 wn = *(const float4*)&W1n[k * 64 + j0];
        acc.x = fmaf(rk, ws.x, acc.x); acc.y = fmaf(rk, ws.y, acc.y);
        acc.z = fmaf(rk, ws.z, acc.z); acc.w = fmaf(rk, ws.w, acc.w);
        acc.x = fmaf(ak, wn.x, acc.x); acc.y = fmaf(ak, wn.y, acc.y);
        acc.z = fmaf(ak, wn.z, acc.z); acc.w = fmaf(ak, wn.w, acc.w);
    }
    uint2 pk;
    pk.x = pack2bf(fmaxf(acc.x, 0.f), fmaxf(acc.y, 0.f));
    pk.y = pack2bf(fmaxf(acc.z, 0.f), fmaxf(acc.w, 0.f));
    *(uint2*)&h1b[(unsigned)n * 32u + (q << 1)] = pk;
}

// one wave per node (4 nodes/block): aggh1b[n] = mean of bf16 h1 rows.
// 16 rows in flight; next iteration's slot indices prefetched.
__global__ __launch_bounds__(256, 8)
void gatherh1_k(const int* __restrict__ off, const int4* __restrict__ slot4,
                const uint4* __restrict__ h1b4, uint4* __restrict__ ah1b4, int N) {
    int n = blockIdx.x * 4 + (threadIdx.x >> 6);
    if (n >= N) return;
    int l = threadIdx.x & 63;
    int g = l >> 3, q = l & 7;
    int s0 = off[n], s1 = off[n + 1];
    float a0 = 0.f, a1 = 0.f, a2 = 0.f, a3 = 0.f;
    float a4 = 0.f, a5 = 0.f, a6 = 0.f, a7 = 0.f;
    int i = s0;
    int nA = 0, nB = 0;
    if (i + 16 <= s1) { nA = slot4[i + g].x; nB = slot4[i + 8 + g].x; }
    for (; i + 16 <= s1; ) {
        int cA = nA, cB = nB;
        int in = i + 16;
        if (in + 16 <= s1) {
            nA = slot4[in + g].x;
            nB = slot4[in + 8 + g].x;
        }
        uint4 v0 = h1b4[(unsigned)cA * 8u + q];
        uint4 v1 = h1b4[(unsigned)cB * 8u + q];
        a0 += bflo(v0.x) + bflo(v1.x); a1 += bfhi(v0.x) + bfhi(v1.x);
        a2 += bflo(v0.y) + bflo(v1.y); a3 += bfhi(v0.y) + bfhi(v1.y);
        a4 += bflo(v0.z) + bflo(v1.z); a5 += bfhi(v0.z) + bfhi(v1.z);
        a6 += bflo(v0.w) + bflo(v1.w); a7 += bfhi(v0.w) + bfhi(v1.w);
        i = in;
    }
    for (; i + 8 <= s1; i += 8) {
        int r = slot4[i + g].x;
        uint4 v = h1b4[(unsigned)r * 8u + q];
        a0 += bflo(v.x); a1 += bfhi(v.x);
        a2 += bflo(v.y); a3 += bfhi(v.y);
        a4 += bflo(v.z); a5 += bfhi(v.z);
        a6 += bflo(v.w); a7 += bfhi(v.w);
    }
    int rem = s1 - i;
    if (g < rem) {
        int r = slot4[i + g].x;
        uint4 v = h1b4[(unsigned)r * 8u + q];
        a0 += bflo(v.x); a1 += bfhi(v.x);
        a2 += bflo(v.y); a3 += bfhi(v.y);
        a4 += bflo(v.z); a5 += bfhi(v.z);
        a6 += bflo(v.w); a7 += bfhi(v.w);
    }
#pragma unroll
    for (int m = 8; m <= 32; m <<= 1) {
        a0 += __shfl_xor(a0, m); a1 += __shfl_xor(a1, m);
        a2 += __shfl_xor(a2, m); a3 += __shfl_xor(a3, m);
        a4 += __shfl_xor(a4, m); a5 += __shfl_xor(a5, m);
        a6 += __shfl_xor(a6, m); a7 += __shfl_xor(a7, m);
    }
    if (l < 8) {
        float invd = 1.f / fmaxf((float)(s1 - s0), 1.f);
        uint4 pk;
        pk.x = pack2bf(a0 * invd, a1 * invd);
        pk.y = pack2bf(a2 * invd, a3 * invd);
        pk.z = pack2bf(a4 * invd, a5 * invd);
        pk.w = pack2bf(a6 * invd, a7 * invd);
        ah1b4[(unsigned)n * 8u + q] = pk;
    }
}

// ---------------------------------------------------------------------------
// MFMA node MLP (unchanged; verified absmax-identical).
// ---------------------------------------------------------------------------
__global__ __launch_bounds__(256)
void node_mlp_mfma_k(const uint4* __restrict__ h1v, const uint4* __restrict__ ahv,
                     const uint4* __restrict__ w2sF, const uint4* __restrict__ w2nF,
                     const uint4* __restrict__ wnpF, const uint4* __restrict__ wbigF,
                     const float* __restrict__ b2, const float* __restrict__ bnp,
                     const float* __restrict__ be1, unsigned short* __restrict__ ST,
                     int N) {
    __shared__ __align__(16) unsigned short Ahi[64][72];
    __shared__ __align__(16) unsigned short Alo[64][72];
    const int t = threadIdx.x;
    const int w = t >> 6, l = t & 63;
    const int lr = l & 15, kq = l >> 4;
    const int m0 = blockIdx.x * 64;
    const int gr = m0 + w * 16 + lr;
    const bool inb = gr < N;
    const int prow = w * 16 + lr;
    const int cbq = kq * 4;

    const uint4 z4 = make_uint4(0u, 0u, 0u, 0u);

    uint4 x1[2], xa[2];
#pragma unroll
    for (int ks = 0; ks < 2; ++ks) {
        unsigned idx = (unsigned)gr * 8u + (unsigned)(ks * 4 + kq);
        x1[ks] = inb ? h1v[idx] : z4;
        xa[ks] = inb ? ahv[idx] : z4;
    }

    // ---- layer 2: h2 = relu(X1@W2s + Xa@W2n + b2) ----
    f32x4 acc[4];
#pragma unroll
    for (int nt = 0; nt < 4; ++nt) acc[nt] = (f32x4){0.f, 0.f, 0.f, 0.f};
#pragma unroll
    for (int ks = 0; ks < 2; ++ks)
#pragma unroll
        for (int nt = 0; nt < 4; ++nt) {
            int base = ((ks * 4 + nt) * 64 + l) * 2;
            acc[nt] = mfma16(w2sF[base],     x1[ks], acc[nt]);
            acc[nt] = mfma16(w2sF[base + 1], x1[ks], acc[nt]);
            acc[nt] = mfma16(w2nF[base],     xa[ks], acc[nt]);
            acc[nt] = mfma16(w2nF[base + 1], xa[ks], acc[nt]);
        }
#pragma unroll
    for (int nt = 0; nt < 4; ++nt) {
        float4 vb = *(const float4*)&b2[nt * 16 + cbq];
        float v0 = fmaxf(acc[nt][0] + vb.x, 0.f);
        float v1 = fmaxf(acc[nt][1] + vb.y, 0.f);
        float v2 = fmaxf(acc[nt][2] + vb.z, 0.f);
        float v3 = fmaxf(acc[nt][3] + vb.w, 0.f);
        unsigned short h0 = f2bf(v0), h1 = f2bf(v1), h2 = f2bf(v2), h3 = f2bf(v3);
        unsigned short q0 = f2bf(v0 - bf2f(h0)), q1 = f2bf(v1 - bf2f(h1));
        unsigned short q2 = f2bf(v2 - bf2f(h2)), q3 = f2bf(v3 - bf2f(h3));
        *(uint2*)&Ahi[prow][nt * 16 + cbq] =
            make_uint2(((unsigned)h1 << 16) | h0, ((unsigned)h3 << 16) | h2);
        *(uint2*)&Alo[prow][nt * 16 + cbq] =
            make_uint2(((unsigned)q1 << 16) | q0, ((unsigned)q3 << 16) | q2);
    }
    __syncthreads();

    uint4 ahi2[2], alo2[2];
#pragma unroll
    for (int ks = 0; ks < 2; ++ks) {
        ahi2[ks] = *(const uint4*)&Ahi[prow][ks * 32 + kq * 8];
        alo2[ks] = *(const uint4*)&Alo[prow][ks * 32 + kq * 8];
    }

    // ---- layer 3: hn = relu(h2@Wnp + bnp) ----
    f32x4 a3[4];
#pragma unroll
    for (int nt = 0; nt < 4; ++nt) a3[nt] = (f32x4){0.f, 0.f, 0.f, 0.f};
#pragma unroll
    for (int ks = 0; ks < 2; ++ks)
#pragma unroll
        for (int nt = 0; nt < 4; ++nt) {
            int base = ((ks * 4 + nt) * 64 + l) * 2;
            a3[nt] = mfma16(wnpF[base],     ahi2[ks], a3[nt]);
            a3[nt] = mfma16(wnpF[base + 1], ahi2[ks], a3[nt]);
            a3[nt] = mfma16(wnpF[base],     alo2[ks], a3[nt]);
        }
#pragma unroll
    for (int nt = 0; nt < 4; ++nt) {
        float4 vb = *(const float4*)&bnp[nt * 16 + cbq];
        float v0 = fmaxf(a3[nt][0] + vb.x, 0.f);
        float v1 = fmaxf(a3[nt][1] + vb.y, 0.f);
        float v2 = fmaxf(a3[nt][2] + vb.z, 0.f);
        float v3 = fmaxf(a3[nt][3] + vb.w, 0.f);
        unsigned short h0 = f2bf(v0), h1 = f2bf(v1), h2 = f2bf(v2), h3 = f2bf(v3);
        unsigned short q0 = f2bf(v0 - bf2f(h0)), q1 = f2bf(v1 - bf2f(h1));
        unsigned short q2 = f2bf(v2 - bf2f(h2)), q3 = f2bf(v3 - bf2f(h3));
        *(uint2*)&Ahi[prow][nt * 16 + cbq] =
            make_uint2(((unsigned)h1 << 16) | h0, ((unsigned)h3 << 16) | h2);
        *(uint2*)&Alo[prow][nt * 16 + cbq] =
            make_uint2(((unsigned)q1 << 16) | q0, ((unsigned)q3 << 16) | q2);
    }
    __syncthreads();

    uint4 bhi[2], blo[2];
#pragma unroll
    for (int ks = 0; ks < 2; ++ks) {
        bhi[ks] = *(const uint4*)&Ahi[prow][ks * 32 + kq * 8];
        blo[ks] = *(const uint4*)&Alo[prow][ks * 32 + kq * 8];
    }

    // ---- layer 4: ST = hn @ Wbig, 16 col-tiles, direct ushort4 stores ----
#pragma unroll
    for (int mtg = 0; mtg < 4; ++mtg) {
        f32x4 a4[4];
#pragma unroll
        for (int m4 = 0; m4 < 4; ++m4) a4[m4] = (f32x4){0.f, 0.f, 0.f, 0.f};
#pragma unroll
        for (int m4 = 0; m4 < 4; ++m4) {
            int mt = mtg * 4 + m4;
#pragma unroll
            for (int ks = 0; ks < 2; ++ks) {
                int base = ((ks * 16 + mt) * 64 + l) * 2;
                a4[m4] = mfma16(wbigF[base],     bhi[ks], a4[m4]);
                a4[m4] = mfma16(wbigF[base + 1], bhi[ks], a4[m4]);
                a4[m4] = mfma16(wbigF[base],     blo[ks], a4[m4]);
            }
        }
#pragma unroll
        for (int m4 = 0; m4 < 4; ++m4) {
            int mt = mtg * 4 + m4;
            int stcb = mt * 16 + cbq;
            float v0 = a4[m4][0], v1 = a4[m4][1], v2 = a4[m4][2], v3 = a4[m4][3];
            if (mt >= 8) {
                int jj0 = (mt - 8) * 8 + kq * 2;
                v0 += be1[jj0];
                v2 += be1[jj0 + 1];
            }
            ushort4 pk;
            pk.x = f2bf(v0); pk.y = f2bf(v1); pk.z = f2bf(v2); pk.w = f2bf(v3);
            if (inb) *(ushort4*)&ST[(unsigned)gr * 256u + (unsigned)stcb] = pk;
        }
    }
}

// ---------------------------------------------------------------------------
// Edge scorer (MFMA, R8-proven form): wave = 16 edges. lane&15 = edge,
// rg = lane>>4 owns output cols tt*16+rg*4..+3 (node_mlp D mapping).
// B-frag comes pre-packed from eb[slot] + slot4.w (sequential stream) --
// no random ef gather. 8 MFMAs; z/o reduced via shfl_xor(16/32); 1-deep
// slot4+eb prefetch; ST gathers issue before the MFMAs for overlap.
// ---------------------------------------------------------------------------
__global__ __launch_bounds__(256)
void edge_k(const int4* __restrict__ slot4, const uint2* __restrict__ eb,
            const unsigned* __restrict__ ST32, const uint4* __restrict__ efragT,
            const float* __restrict__ We2, const float* __restrict__ be2,
            const float* __restrict__ bl1, const float* __restrict__ Wl2,
            const float* __restrict__ bl2, float* __restrict__ out,
            int E, int nwaves) {
    const int l = threadIdx.x & 63;
    const int e4 = l & 15;               // edge within 16-edge group
    const int rg = l >> 4;               // row-group: cols tt*16 + rg*4 .. +3
    const int rg4 = rg << 2;
    const int wid = blockIdx.x * (blockDim.x >> 6) + (threadIdx.x >> 6);
    const int ng = (E + 15) >> 4;
    const float vbe2 = be2[0], vbl2 = bl2[0];
    const bool bzero = rg >= 2;          // B-frag zero for k >= 16
    const uint4 z4u = make_uint4(0u, 0u, 0u, 0u);
    const f32x4 zf = {0.f, 0.f, 0.f, 0.f};

    // prologue prefetch (group wid)
    int4 sv; uint4 bfr; bool act;
    {
        int s = wid * 16 + e4;
        act = (wid < ng) && (s < E);
        unsigned u = act ? (unsigned)s : 0u;
        sv = slot4[u];
        uint2 ev = eb[u];
        bfr = bzero ? z4u : make_uint4(ev.x, ev.y, (unsigned)sv.w, 0u);
    }

    for (int g = wid; g < ng; ) {
        int gn = g + nwaves;
        // prefetch next group's slot4 + eb B-frag
        int4 svn; uint4 bfn; bool actn;
        {
            int s = gn * 16 + e4;
            actn = (gn < ng) && (s < E);
            unsigned u = actn ? (unsigned)s : 0u;
            svn = slot4[u];
            uint2 ev = eb[u];
            bfn = bzero ? z4u : make_uint4(ev.x, ev.y, (unsigned)svn.w, 0u);
        }

        // issue all 8 ST gathers (latency hides under MFMAs below)
        unsigned srb = (unsigned)sv.x * 128u + (unsigned)rg4;
        unsigned drb = (unsigned)sv.z * 128u + 64u + (unsigned)rg4;
        uint4 sw0 = *(const uint4*)&ST32[srb];
        uint4 sw1 = *(const uint4*)&ST32[srb + 16u];
        uint4 sw2 = *(const uint4*)&ST32[srb + 32u];
        uint4 sw3 = *(const uint4*)&ST32[srb + 48u];
        uint4 pw0 = *(const uint4*)&ST32[drb];
        uint4 pw1 = *(const uint4*)&ST32[drb + 16u];
        uint4 pw2 = *(const uint4*)&ST32[drb + 32u];
        uint4 pw3 = *(const uint4*)&ST32[drb + 48u];

        // 8 MFMAs: D[m=out-col][n=edge]; hi/lo compensated via K-folding
        f32x4 dt0 = mfma16(efragT[0 * 64 + l], bfr, zf);
        f32x4 dt1 = mfma16(efragT[1 * 64 + l], bfr, zf);
        f32x4 dt2 = mfma16(efragT[2 * 64 + l], bfr, zf);
        f32x4 dt3 = mfma16(efragT[3 * 64 + l], bfr, zf);
        f32x4 du0 = mfma16(efragT[4 * 64 + l], bfr, zf);
        f32x4 du1 = mfma16(efragT[5 * 64 + l], bfr, zf);
        f32x4 du2 = mfma16(efragT[6 * 64 + l], bfr, zf);
        f32x4 du3 = mfma16(efragT[7 * 64 + l], bfr, zf);

        // t path: z = sum_c tanh(t_c) * We2_c   (be1 pre-folded into pw lo)
        float z = 0.f;
#define TT(i, DT, SW, PW) { \
        float4 w2v = *(const float4*)&We2[(i) * 16 + rg4]; \
        z = fmaf(fast_tanh(DT[0] + bflo(SW.x) + bflo(PW.x)), w2v.x, z); \
        z = fmaf(fast_tanh(DT[1] + bflo(SW.y) + bflo(PW.y)), w2v.y, z); \
        z = fmaf(fast_tanh(DT[2] + bflo(SW.z) + bflo(PW.z)), w2v.z, z); \
        z = fmaf(fast_tanh(DT[3] + bflo(SW.w) + bflo(PW.w)), w2v.w, z); }
        TT(0, dt0, sw0, pw0)
        TT(1, dt1, sw1, pw1)
        TT(2, dt2, sw2, pw2)
        TT(3, dt3, sw3, pw3)
#undef TT
        z += __shfl_xor(z, 16);
        z += __shfl_xor(z, 32);
        float w = fast_sigmoid(z + vbe2);

        // u path: o = sum_c relu(w*u_c + bl1_c) * Wl2_c
        float o = 0.f;
#define UT(i, DU, SW, PW) { \
        float4 blv = *(const float4*)&bl1[(i) * 16 + rg4]; \
        float4 wlv = *(const float4*)&Wl2[(i) * 16 + rg4]; \
        o = fmaf(fmaxf(fmaf(w, DU[0] + bfhi(SW.x) + bfhi(PW.x), blv.x), 0.f), wlv.x, o); \
        o = fmaf(fmaxf(fmaf(w, DU[1] + bfhi(SW.y) + bfhi(PW.y), blv.y), 0.f), wlv.y, o); \
        o = fmaf(fmaxf(fmaf(w, DU[2] + bfhi(SW.z) + bfhi(PW.z), blv.z), 0.f), wlv.z, o); \
        o = fmaf(fmaxf(fmaf(w, DU[3] + bfhi(SW.w) + bfhi(PW.w), blv.w), 0.f), wlv.w, o); }
        UT(0, du0, sw0, pw0)
        UT(1, du1, sw1, pw1)
        UT(2, du2, sw2, pw2)
        UT(3, du3, sw3, pw3)
#undef UT
        o += __shfl_xor(o, 16);
        o += __shfl_xor(o, 32);
        if (rg == 0 && act) out[(unsigned)sv.y] = o + vbl2;

        sv = svn; bfr = bfn; act = actn;
        g = gn;
    }
}

extern "C" void kernel_launch(void* const* d_in, const int* in_sizes, int n_in,
                              void* d_out, int out_size, void* d_ws, size_t ws_size,
                              hipStream_t stream) {
    const float* nf  = (const float*)d_in[0];
    const float* ef  = (const float*)d_in[1];
    const int*   src = (const int*)d_in[2];
    const int*   dst = (const int*)d_in[3];
    const float* W1s = (const float*)d_in[4];
    const float* W1n = (const float*)d_in[5];
    const float* b1  = (const float*)d_in[6];
    const float* W2s = (const float*)d_in[7];
    const float* W2n = (const float*)d_in[8];
    const float* b2  = (const float*)d_in[9];
    const float* Wnp = (const float*)d_in[10];
    const float* bnp = (const float*)d_in[11];
    const float* We1 = (const float*)d_in[12];
    const float* be1 = (const float*)d_in[13];
    const float* We2 = (const float*)d_in[14];
    const float* be2 = (const float*)d_in[15];
    const float* Wl1 = (const float*)d_in[16];
    const float* bl1 = (const float*)d_in[17];
    const float* Wl2 = (const float*)d_in[18];
    const float* bl2 = (const float*)d_in[19];

    const int N = in_sizes[0] / 4;
    const int E = in_sizes[2];

    // ws layout (float units), peak ~305N + 31K floats ≈ 122.1 MB (<128 MB):
    //  ST(bf16): [0, 128N)           written by node_mlp_mfma, read by edge_k
    //  ah1b:     [128N, 160N)        packed bf16 aggh1 (uint[32N])
    //  wfrag:    [160N, 160N+30720)  MFMA weight frags 7680 uint4 (120KB)
    //  h1b:      [160N+30720, +32N)  packed bf16 h1 (uint[32N])
    //  slot4:    [192N+30720, +64N)  int4[E] {src, eid, dst, packbf(ef4)}
    //  eb:       [256N+30720, +32N)  uint2[E] slot-ordered bf16 ef pairs
    //  rank:     [288N+30720, +16N)  int[E]
    //  deg:      [304N+30720, +N)    int[N]
    //  off:      deg+N, N+1          int[N+1]
    //  bsum:     off+N+1             int[512]
    float* wsf = (float*)d_ws;
    unsigned short* ST = (unsigned short*)wsf;
    unsigned* ah1b = (unsigned*)(wsf + (size_t)128 * N);
    uint4* w2sF   = (uint4*)(wsf + (size_t)160 * N);
    uint4* w2nF   = w2sF + 1024;
    uint4* wnpF   = w2sF + 2048;
    uint4* wbigF  = w2sF + 3072;
    uint4* efragT = w2sF + 7168;   // 512 uint4 -> ends at 7680 uint4
    unsigned* h1b  = (unsigned*)(wsf + (size_t)160 * N + 30720);
    int4* slot4 = (int4*)(wsf + (size_t)192 * N + 30720);
    uint2* eb   = (uint2*)(wsf + (size_t)256 * N + 30720);
    int*  rank = (int*)(wsf + (size_t)288 * N + 30720);
    int*  deg  = (int*)(wsf + (size_t)304 * N + 30720);
    int*  off  = deg + N;
    int*  bsum = off + N + 1;
    float* out = (float*)d_out;

    const int nblkN1 = (N + 255) / 256;
    const int nblkE  = (E + 255) / 256;
    const int nblkNw4 = (N + 3) / 4;      // 256-thread, 4 nodes (gatherh1)
    const int nblkN16 = (N + 15) / 16;    // 256-thread, 16 nodes (aggh1f)
    const int gemmx  = (N + 63) / 64;
    const int EDGE_BLOCKS = 3072;
    const int nwaves = EDGE_BLOCKS * 4;

    // weight frag prep (depends only on inputs; run first)
    prep_w_k<<<5, 256, 0, stream>>>(W2s, W2n, Wnp, We1, Wl1,
                                    w2sF, w2nF, wnpF, wbigF, efragT);

    // CSR build: single atomic pass (rank) + scan + atomic-free fill (+eb)
    hipMemsetAsync(deg, 0, (size_t)N * sizeof(int), stream);
    rank_k<<<nblkE, 256, 0, stream>>>(dst, deg, rank, E);
    scan1_k<<<nblkN1, 256, 0, stream>>>(deg, off, bsum, N);
    scan2_k<<<1, 512, 0, stream>>>(bsum, nblkN1);
    scan3_k<<<nblkN1, 256, 0, stream>>>(off, bsum, N, E);
    fill2_k<<<nblkE, 256, 0, stream>>>(src, dst, off, rank, ef, slot4, eb, E);

    // layer 1 (fused aggregate + h1, bf16 out; quarter-wave per node)
    aggh1f_k<<<nblkN16, 256, 0, stream>>>(off, slot4, nf, W1s, W1n, b1, h1b, N);

    // layer 2 gather (bf16 out, uint4, 16 rows in flight, index prefetch)
    gatherh1_k<<<nblkNw4, 256, 0, stream>>>(off, slot4, (const uint4*)h1b,
                                            (uint4*)ah1b, N);

    // fused node MLP on matrix cores -> bf16 ST table
    node_mlp_mfma_k<<<gemmx, 256, 0, stream>>>((const uint4*)h1b, (const uint4*)ah1b,
                                               w2sF, w2nF, wnpF, wbigF,
                                               b2, bnp, be1, ST, N);

    // per-edge scoring (MFMA ef-offload, slot-ordered eb stream)
    edge_k<<<EDGE_BLOCKS, 256, 0, stream>>>(slot4, eb, (const unsigned*)ST,
                                            efragT, We2, be2, bl1, Wl2, bl2,
                                            out, E, nwaves);
}

// Round 11
// 460.862 us; speedup vs baseline: 1.0191x; 1.0191x over previous
//
#include <hip/hip_runtime.h>
#include <math.h>

// ---------------------------------------------------------------------------
// EdgeClassifier: 2x SAGEConv(mean) -> per-node MLP -> edge scorer
//  * layer-1 agg: mean commutes with projection -> aggregate raw nf (4-dim),
//    fused with h1 compute; quarter-wave (16 lanes) per node, DPP all-reduce
//  * CSR: rank_k (atomic returning rank) + scan + atomic-free fill into ONE
//    24B record stream rec6 = uint2[3E]: {src,eid},{dst,packbf(e4)},
//    {eb01,eb23}. R10 lesson: slot4+eb as TWO scatter streams cost the fill
//    ~+35us (temporally-scattered partial-line sectors, one tax per
//    stream); one contiguous 24B scatter pays the R8-level tax once while
//    keeping edge_k's sequential pre-packed ef (the R10 win: edge_k FETCH
//    322->215MB, 131->103us).
//  * gatherh1/aggh1f: 1-deep slot-index prefetch; src at rec6[3i].x
//  * node_mlp_mfma_k: MFMA (16x16x32 bf16) node MLP; weights pre-split
//    hi/lo bf16 (prep_w_k); swapped operands -> direct ushort4 ST stores.
//  * edge_k: R8/R10 MFMA form; level-1 = 3 sequential uint2 loads.
//    EVIDENCE LEDGER: edge_k is FETCH-bound (R4=R8=R9 at 131-133us until
//    bytes dropped in R10). R9 deep pipeline RETIRED (null, occ 20%).
//    Packed-f2 RETIRED (R3/R5 spills). R6 atomic-claim fill RETIRED.
//    TRIPWIRES: WRITE>60MB = spill -> revert; absmax != 4.882812e-4 ->
//    record-path bug -> revert; E2E>455 -> fill-scatter theory wrong ->
//    revert to exact R8.
// ---------------------------------------------------------------------------

typedef __attribute__((ext_vector_type(8))) short bf16x8;
typedef __attribute__((ext_vector_type(4))) float f32x4;

__device__ __forceinline__ float fast_tanh(float x) {
    x = fminf(fmaxf(x, -15.f), 15.f);
    float e2 = __expf(2.f * x);
    return (e2 - 1.f) * __builtin_amdgcn_rcpf(e2 + 1.f);
}
__device__ __forceinline__ float fast_sigmoid(float x) {
    x = fminf(fmaxf(x, -60.f), 60.f);
    return __builtin_amdgcn_rcpf(1.f + __expf(-x));
}
__device__ __forceinline__ unsigned short f2bf(float f) {   // RNE
    unsigned u = __float_as_uint(f);
    u = u + 0x7FFFu + ((u >> 16) & 1u);
    return (unsigned short)(u >> 16);
}
__device__ __forceinline__ unsigned pack2bf(float lo, float hi) {
    return ((unsigned)f2bf(hi) << 16) | (unsigned)f2bf(lo);
}
__device__ __forceinline__ float bflo(unsigned u) { return __uint_as_float(u << 16); }
__device__ __forceinline__ float bfhi(unsigned u) { return __uint_as_float(u & 0xFFFF0000u); }
__device__ __forceinline__ float bf2f(unsigned short h) {
    return __uint_as_float((unsigned)h << 16);
}

__device__ __forceinline__ f32x4 mfma16(uint4 a, uint4 b, f32x4 c) {
    return __builtin_amdgcn_mfma_f32_16x16x32_bf16(
        __builtin_bit_cast(bf16x8, a), __builtin_bit_cast(bf16x8, b), c, 0, 0, 0);
}

// 16-lane all-reduce sum, pure DPP (no LDS/DS); reduces within 16-lane rows
__device__ __forceinline__ float dpp_sum16(float x) {
    int t;
    t = __builtin_amdgcn_update_dpp(0, __float_as_int(x), 0xB1, 0xF, 0xF, true);  // quad_perm(1,0,3,2)
    x += __int_as_float(t);
    t = __builtin_amdgcn_update_dpp(0, __float_as_int(x), 0x4E, 0xF, 0xF, true);  // quad_perm(2,3,0,1)
    x += __int_as_float(t);
    t = __builtin_amdgcn_update_dpp(0, __float_as_int(x), 0x141, 0xF, 0xF, true); // row_half_mirror
    x += __int_as_float(t);
    t = __builtin_amdgcn_update_dpp(0, __float_as_int(x), 0x140, 0xF, 0xF, true); // row_mirror
    x += __int_as_float(t);
    return x;
}

// rank[e] = arrival index among edges sharing dst; deg accumulates counts
__global__ void rank_k(const int* __restrict__ dst, int* __restrict__ deg,
                       int* __restrict__ rank, int E) {
    int e = blockIdx.x * blockDim.x + threadIdx.x;
    if (e < E) rank[e] = atomicAdd(&deg[dst[e]], 1);
}

__global__ void scan1_k(const int* __restrict__ deg, int* __restrict__ off,
                        int* __restrict__ bsum, int N) {
    __shared__ int tmp[256];
    int i = blockIdx.x * 256 + threadIdx.x;
    int v = (i < N) ? deg[i] : 0;
    tmp[threadIdx.x] = v;
    __syncthreads();
#pragma unroll
    for (int s = 1; s < 256; s <<= 1) {
        int t = (threadIdx.x >= s) ? tmp[threadIdx.x - s] : 0;
        __syncthreads();
        tmp[threadIdx.x] += t;
        __syncthreads();
    }
    if (i < N) off[i] = tmp[threadIdx.x] - v;
    if (threadIdx.x == 255) bsum[blockIdx.x] = tmp[255];
}

__global__ void scan2_k(int* __restrict__ bsum, int nb) {
    __shared__ int tmp[512];
    int i = threadIdx.x;
    int v = (i < nb) ? bsum[i] : 0;
    tmp[i] = v;
    __syncthreads();
#pragma unroll
    for (int s = 1; s < 512; s <<= 1) {
        int t = (i >= s) ? tmp[i - s] : 0;
        __syncthreads();
        tmp[i] += t;
        __syncthreads();
    }
    if (i < nb) bsum[i] = tmp[i] - v;
}

__global__ void scan3_k(int* __restrict__ off, const int* __restrict__ bsum,
                        int N, int E) {
    int i = blockIdx.x * 256 + threadIdx.x;
    if (i < N) off[i] += bsum[blockIdx.x];
    if (i == 0) off[N] = E;
}

// atomic-free CSR fill: ONE contiguous 24B record per edge (3x uint2 stores
// to consecutive addresses -> single scatter span, ~1 line/edge).
// rec6[3p]={src,eid}, rec6[3p+1]={dst,packbf(e4)}, rec6[3p+2]={eb01,eb23}.
__global__ void fill2_k(const int* __restrict__ src, const int* __restrict__ dst,
                        const int* __restrict__ off, const int* __restrict__ rank,
                        const float* __restrict__ ef,
                        uint2* __restrict__ rec6, int E) {
    int e = blockIdx.x * blockDim.x + threadIdx.x;
    if (e >= E) return;
    int d = dst[e];
    int pos = off[d] + rank[e];
    const float* ep = ef + (size_t)e * 5;
    float e0 = ep[0], e1 = ep[1], e2 = ep[2], e3 = ep[3], e4 = ep[4];
    unsigned base = (unsigned)pos * 3u;
    rec6[base]     = make_uint2((unsigned)src[e], (unsigned)e);
    rec6[base + 1] = make_uint2((unsigned)d, pack2bf(e4, 0.f));
    rec6[base + 2] = make_uint2(pack2bf(e0, e1), pack2bf(e2, e3));
}

// ---------------------------------------------------------------------------
// Weight prep (runs once): MFMA fragment-layout hi/lo bf16 copies, plus
// edge A-frag table efragT[8][64]: tiles 0..3 = We1 rows 128..132 (t path),
// tiles 4..7 = Wl1 rows 128..132 (u path). kq==0 lanes carry hi bf16 at
// k=0..4; kq==1 lanes carry lo residual at k=8..12 (hi/lo-in-K trick:
// B duplicates ef in both k ranges, one MFMA sums both products).
// ---------------------------------------------------------------------------
__global__ void prep_w_k(const float* __restrict__ W2s, const float* __restrict__ W2n,
                         const float* __restrict__ Wnp, const float* __restrict__ We1,
                         const float* __restrict__ Wl1, uint4* __restrict__ w2sF,
                         uint4* __restrict__ w2nF, uint4* __restrict__ wnpF,
                         uint4* __restrict__ wbigF, uint4* __restrict__ efragT) {
    const int b = blockIdx.x, t = threadIdx.x;
    if (b < 3) {
        const float* W = (b == 0) ? W2s : (b == 1) ? W2n : Wnp;
        uint4* out = (b == 0) ? w2sF : (b == 1) ? w2nF : wnpF;
        for (int u = t; u < 2 * 4 * 64; u += 256) {
            int l = u & 63, nt = (u >> 6) & 3, ks = u >> 8;
            int m = nt * 16 + (l & 15), kb = ks * 32 + (l >> 4) * 8;
            unsigned hi[4], lo[4];
#pragma unroll
            for (int jp = 0; jp < 4; ++jp) {
                float v0 = W[(kb + 2 * jp) * 64 + m];
                float v1 = W[(kb + 2 * jp + 1) * 64 + m];
                unsigned short h0 = f2bf(v0), h1 = f2bf(v1);
                unsigned short q0 = f2bf(v0 - bf2f(h0)), q1 = f2bf(v1 - bf2f(h1));
                hi[jp] = ((unsigned)h1 << 16) | h0;
                lo[jp] = ((unsigned)q1 << 16) | q0;
            }
            out[u * 2]     = make_uint4(hi[0], hi[1], hi[2], hi[3]);
            out[u * 2 + 1] = make_uint4(lo[0], lo[1], lo[2], lo[3]);
        }
    } else if (b == 3) {
        for (int u = t; u < 2 * 16 * 64; u += 256) {
            int l = u & 63, nt = (u >> 6) & 15, ks = u >> 10;
            int m = nt * 16 + (l & 15), kb = ks * 32 + (l >> 4) * 8;
            int half = m >> 7, cc = m & 127, jj = cc >> 1, p = cc & 1;
            const float* W = p ? Wl1 : We1;
            unsigned hi[4], lo[4];
#pragma unroll
            for (int jp = 0; jp < 4; ++jp) {
                float v0 = W[(half * 64 + kb + 2 * jp) * 64 + jj];
                float v1 = W[(half * 64 + kb + 2 * jp + 1) * 64 + jj];
                unsigned short h0 = f2bf(v0), h1 = f2bf(v1);
                unsigned short q0 = f2bf(v0 - bf2f(h0)), q1 = f2bf(v1 - bf2f(h1));
                hi[jp] = ((unsigned)h1 << 16) | h0;
                lo[jp] = ((unsigned)q1 << 16) | q0;
            }
            wbigF[u * 2]     = make_uint4(hi[0], hi[1], hi[2], hi[3]);
            wbigF[u * 2 + 1] = make_uint4(lo[0], lo[1], lo[2], lo[3]);
        }
    } else {
        for (int u = t; u < 8 * 64; u += 256) {
            int l = u & 63, tile = u >> 6;
            int kq = l >> 4, m16 = l & 15;
            const float* W = (tile < 4) ? We1 : Wl1;
            int c = (tile & 3) * 16 + m16;
            unsigned uu0 = 0u, uu1 = 0u, uu2 = 0u;
            if (kq < 2) {
                float v[5];
#pragma unroll
                for (int j = 0; j < 5; ++j) {
                    float wv = W[(128 + j) * 64 + c];
                    unsigned short h = f2bf(wv);
                    v[j] = (kq == 0) ? bf2f(h) : (wv - bf2f(h));
                }
                uu0 = pack2bf(v[0], v[1]);
                uu1 = pack2bf(v[2], v[3]);
                uu2 = pack2bf(v[4], 0.f);
            }
            efragT[tile * 64 + l] = make_uint4(uu0, uu1, uu2, 0u);
        }
    }
}

// quarter-wave (16 lanes) per node, 16 nodes/block: aggnf = mean of
// nf[neighbors] (stride-16 gather + DPP-16 all-reduce, 1-deep index
// prefetch), then lane q computes h1 cols 4q..4q+3, packed bf16.
__global__ __launch_bounds__(256, 8)
void aggh1f_k(const int* __restrict__ off, const uint2* __restrict__ rec6,
              const float* __restrict__ nf,
              const float* __restrict__ W1s, const float* __restrict__ W1n,
              const float* __restrict__ b1, unsigned* __restrict__ h1b, int N) {
    int n = blockIdx.x * 16 + (threadIdx.x >> 4);
    if (n >= N) return;
    int q = threadIdx.x & 15;
    int s0 = off[n], s1 = off[n + 1];
    const float4* nf4 = (const float4*)nf;
    float4 a = {0.f, 0.f, 0.f, 0.f};
    int i = s0 + q;
    unsigned nx = (i < s1) ? rec6[(unsigned)i * 3u].x : 0u;
    for (; i < s1; ) {
        unsigned cur = nx;
        int in = i + 16;
        if (in < s1) nx = rec6[(unsigned)in * 3u].x;   // prefetch next index
        float4 r = nf4[cur];
        a.x += r.x; a.y += r.y; a.z += r.z; a.w += r.w;
        i = in;
    }
    a.x = dpp_sum16(a.x);
    a.y = dpp_sum16(a.y);
    a.z = dpp_sum16(a.z);
    a.w = dpp_sum16(a.w);
    float invd = 1.f / fmaxf((float)(s1 - s0), 1.f);
    a.x *= invd; a.y *= invd; a.z *= invd; a.w *= invd;
    float4 r = nf4[(unsigned)n];
    const int j0 = q << 2;
    float4 acc = *(const float4*)&b1[j0];
#pragma unroll
    for (int k = 0; k < 4; ++k) {
        float rk = (k == 0) ? r.x : (k == 1) ? r.y : (k == 2) ? r.z : r.w;
        float ak = (k == 0) ? a.x : (k == 1) ? a.y : (k == 2) ? a.z : a.w;
        float4 ws = *(const float4*)&W1s[k * 64 + j0];
        float4 wn = *(const float4*)&W1n[k * 64 + j0];
        acc.x = fmaf(rk, ws.x, acc.x); acc.y = fmaf(rk, ws.y, acc.y);
        acc.z = fmaf(rk, ws.z, acc.z); acc.w = fmaf(rk, ws.w, acc.w);
        acc.x = fmaf(ak, wn.x, acc.x); acc.y = fmaf(ak, wn.y, acc.y);
        acc.z = fmaf(ak, wn.z, acc.z); acc.w = fmaf(ak, wn.w, acc.w);
    }
    uint2 pk;
    pk.x = pack2bf(fmaxf(acc.x, 0.f), fmaxf(acc.y, 0.f));
    pk.y = pack2bf(fmaxf(acc.z, 0.f), fmaxf(acc.w, 0.f));
    *(uint2*)&h1b[(unsigned)n * 32u + (q << 1)] = pk;
}

// one wave per node (4 nodes/block): aggh1b[n] = mean of bf16 h1 rows.
// 16 rows in flight; next iteration's slot indices prefetched.
__global__ __launch_bounds__(256, 8)
void gatherh1_k(const int* __restrict__ off, const uint2* __restrict__ rec6,
                const uint4* __restrict__ h1b4, uint4* __restrict__ ah1b4, int N) {
    int n = blockIdx.x * 4 + (threadIdx.x >> 6);
    if (n >= N) return;
    int l = threadIdx.x & 63;
    int g = l >> 3, q = l & 7;
    int s0 = off[n], s1 = off[n + 1];
    float a0 = 0.f, a1 = 0.f, a2 = 0.f, a3 = 0.f;
    float a4 = 0.f, a5 = 0.f, a6 = 0.f, a7 = 0.f;
    int i = s0;
    unsigned nA = 0u, nB = 0u;
    if (i + 16 <= s1) {
        nA = rec6[(unsigned)(i + g) * 3u].x;
        nB = rec6[(unsigned)(i + 8 + g) * 3u].x;
    }
    for (; i + 16 <= s1; ) {
        unsigned cA = nA, cB = nB;
        int in = i + 16;
        if (in + 16 <= s1) {                 // prefetch next pair of indices
            nA = rec6[(unsigned)(in + g) * 3u].x;
            nB = rec6[(unsigned)(in + 8 + g) * 3u].x;
        }
        uint4 v0 = h1b4[cA * 8u + q];
        uint4 v1 = h1b4[cB * 8u + q];
        a0 += bflo(v0.x) + bflo(v1.x); a1 += bfhi(v0.x) + bfhi(v1.x);
        a2 += bflo(v0.y) + bflo(v1.y); a3 += bfhi(v0.y) + bfhi(v1.y);
        a4 += bflo(v0.z) + bflo(v1.z); a5 += bfhi(v0.z) + bfhi(v1.z);
        a6 += bflo(v0.w) + bflo(v1.w); a7 += bfhi(v0.w) + bfhi(v1.w);
        i = in;
    }
    for (; i + 8 <= s1; i += 8) {
        unsigned r = rec6[(unsigned)(i + g) * 3u].x;
        uint4 v = h1b4[r * 8u + q];
        a0 += bflo(v.x); a1 += bfhi(v.x);
        a2 += bflo(v.y); a3 += bfhi(v.y);
        a4 += bflo(v.z); a5 += bfhi(v.z);
        a6 += bflo(v.w); a7 += bfhi(v.w);
    }
    int rem = s1 - i;
    if (g < rem) {
        unsigned r = rec6[(unsigned)(i + g) * 3u].x;
        uint4 v = h1b4[r * 8u + q];
        a0 += bflo(v.x); a1 += bfhi(v.x);
        a2 += bflo(v.y); a3 += bfhi(v.y);
        a4 += bflo(v.z); a5 += bfhi(v.z);
        a6 += bflo(v.w); a7 += bfhi(v.w);
    }
#pragma unroll
    for (int m = 8; m <= 32; m <<= 1) {
        a0 += __shfl_xor(a0, m); a1 += __shfl_xor(a1, m);
        a2 += __shfl_xor(a2, m); a3 += __shfl_xor(a3, m);
        a4 += __shfl_xor(a4, m); a5 += __shfl_xor(a5, m);
        a6 += __shfl_xor(a6, m); a7 += __shfl_xor(a7, m);
    }
    if (l < 8) {
        float invd = 1.f / fmaxf((float)(s1 - s0), 1.f);
        uint4 pk;
        pk.x = pack2bf(a0 * invd, a1 * invd);
        pk.y = pack2bf(a2 * invd, a3 * invd);
        pk.z = pack2bf(a4 * invd, a5 * invd);
        pk.w = pack2bf(a6 * invd, a7 * invd);
        ah1b4[(unsigned)n * 8u + q] = pk;
    }
}

// ---------------------------------------------------------------------------
// MFMA node MLP (unchanged; verified absmax-identical).
// ---------------------------------------------------------------------------
__global__ __launch_bounds__(256)
void node_mlp_mfma_k(const uint4* __restrict__ h1v, const uint4* __restrict__ ahv,
                     const uint4* __restrict__ w2sF, const uint4* __restrict__ w2nF,
                     const uint4* __restrict__ wnpF, const uint4* __restrict__ wbigF,
                     const float* __restrict__ b2, const float* __restrict__ bnp,
                     const float* __restrict__ be1, unsigned short* __restrict__ ST,
                     int N) {
    __shared__ __align__(16) unsigned short Ahi[64][72];
    __shared__ __align__(16) unsigned short Alo[64][72];
    const int t = threadIdx.x;
    const int w = t >> 6, l = t & 63;
    const int lr = l & 15, kq = l >> 4;
    const int m0 = blockIdx.x * 64;
    const int gr = m0 + w * 16 + lr;
    const bool inb = gr < N;
    const int prow = w * 16 + lr;
    const int cbq = kq * 4;

    const uint4 z4 = make_uint4(0u, 0u, 0u, 0u);

    uint4 x1[2], xa[2];
#pragma unroll
    for (int ks = 0; ks < 2; ++ks) {
        unsigned idx = (unsigned)gr * 8u + (unsigned)(ks * 4 + kq);
        x1[ks] = inb ? h1v[idx] : z4;
        xa[ks] = inb ? ahv[idx] : z4;
    }

    // ---- layer 2: h2 = relu(X1@W2s + Xa@W2n + b2) ----
    f32x4 acc[4];
#pragma unroll
    for (int nt = 0; nt < 4; ++nt) acc[nt] = (f32x4){0.f, 0.f, 0.f, 0.f};
#pragma unroll
    for (int ks = 0; ks < 2; ++ks)
#pragma unroll
        for (int nt = 0; nt < 4; ++nt) {
            int base = ((ks * 4 + nt) * 64 + l) * 2;
            acc[nt] = mfma16(w2sF[base],     x1[ks], acc[nt]);
            acc[nt] = mfma16(w2sF[base + 1], x1[ks], acc[nt]);
            acc[nt] = mfma16(w2nF[base],     xa[ks], acc[nt]);
            acc[nt] = mfma16(w2nF[base + 1], xa[ks], acc[nt]);
        }
#pragma unroll
    for (int nt = 0; nt < 4; ++nt) {
        float4 vb = *(const float4*)&b2[nt * 16 + cbq];
        float v0 = fmaxf(acc[nt][0] + vb.x, 0.f);
        float v1 = fmaxf(acc[nt][1] + vb.y, 0.f);
        float v2 = fmaxf(acc[nt][2] + vb.z, 0.f);
        float v3 = fmaxf(acc[nt][3] + vb.w, 0.f);
        unsigned short h0 = f2bf(v0), h1 = f2bf(v1), h2 = f2bf(v2), h3 = f2bf(v3);
        unsigned short q0 = f2bf(v0 - bf2f(h0)), q1 = f2bf(v1 - bf2f(h1));
        unsigned short q2 = f2bf(v2 - bf2f(h2)), q3 = f2bf(v3 - bf2f(h3));
        *(uint2*)&Ahi[prow][nt * 16 + cbq] =
            make_uint2(((unsigned)h1 << 16) | h0, ((unsigned)h3 << 16) | h2);
        *(uint2*)&Alo[prow][nt * 16 + cbq] =
            make_uint2(((unsigned)q1 << 16) | q0, ((unsigned)q3 << 16) | q2);
    }
    __syncthreads();

    uint4 ahi2[2], alo2[2];
#pragma unroll
    for (int ks = 0; ks < 2; ++ks) {
        ahi2[ks] = *(const uint4*)&Ahi[prow][ks * 32 + kq * 8];
        alo2[ks] = *(const uint4*)&Alo[prow][ks * 32 + kq * 8];
    }

    // ---- layer 3: hn = relu(h2@Wnp + bnp) ----
    f32x4 a3[4];
#pragma unroll
    for (int nt = 0; nt < 4; ++nt) a3[nt] = (f32x4){0.f, 0.f, 0.f, 0.f};
#pragma unroll
    for (int ks = 0; ks < 2; ++ks)
#pragma unroll
        for (int nt = 0; nt < 4; ++nt) {
            int base = ((ks * 4 + nt) * 64 + l) * 2;
            a3[nt] = mfma16(wnpF[base],     ahi2[ks], a3[nt]);
            a3[nt] = mfma16(wnpF[base + 1], ahi2[ks], a3[nt]);
            a3[nt] = mfma16(wnpF[base],     alo2[ks], a3[nt]);
        }
#pragma unroll
    for (int nt = 0; nt < 4; ++nt) {
        float4 vb = *(const float4*)&bnp[nt * 16 + cbq];
        float v0 = fmaxf(a3[nt][0] + vb.x, 0.f);
        float v1 = fmaxf(a3[nt][1] + vb.y, 0.f);
        float v2 = fmaxf(a3[nt][2] + vb.z, 0.f);
        float v3 = fmaxf(a3[nt][3] + vb.w, 0.f);
        unsigned short h0 = f2bf(v0), h1 = f2bf(v1), h2 = f2bf(v2), h3 = f2bf(v3);
        unsigned short q0 = f2bf(v0 - bf2f(h0)), q1 = f2bf(v1 - bf2f(h1));
        unsigned short q2 = f2bf(v2 - bf2f(h2)), q3 = f2bf(v3 - bf2f(h3));
        *(uint2*)&Ahi[prow][nt * 16 + cbq] =
            make_uint2(((unsigned)h1 << 16) | h0, ((unsigned)h3 << 16) | h2);
        *(uint2*)&Alo[prow][nt * 16 + cbq] =
            make_uint2(((unsigned)q1 << 16) | q0, ((unsigned)q3 << 16) | q2);
    }
    __syncthreads();

    uint4 bhi[2], blo[2];
#pragma unroll
    for (int ks = 0; ks < 2; ++ks) {
        bhi[ks] = *(const uint4*)&Ahi[prow][ks * 32 + kq * 8];
        blo[ks] = *(const uint4*)&Alo[prow][ks * 32 + kq * 8];
    }

    // ---- layer 4: ST = hn @ Wbig, 16 col-tiles, direct ushort4 stores ----
#pragma unroll
    for (int mtg = 0; mtg < 4; ++mtg) {
        f32x4 a4[4];
#pragma unroll
        for (int m4 = 0; m4 < 4; ++m4) a4[m4] = (f32x4){0.f, 0.f, 0.f, 0.f};
#pragma unroll
        for (int m4 = 0; m4 < 4; ++m4) {
            int mt = mtg * 4 + m4;
#pragma unroll
            for (int ks = 0; ks < 2; ++ks) {
                int base = ((ks * 16 + mt) * 64 + l) * 2;
                a4[m4] = mfma16(wbigF[base],     bhi[ks], a4[m4]);
                a4[m4] = mfma16(wbigF[base + 1], bhi[ks], a4[m4]);
                a4[m4] = mfma16(wbigF[base],     blo[ks], a4[m4]);
            }
        }
#pragma unroll
        for (int m4 = 0; m4 < 4; ++m4) {
            int mt = mtg * 4 + m4;
            int stcb = mt * 16 + cbq;
            float v0 = a4[m4][0], v1 = a4[m4][1], v2 = a4[m4][2], v3 = a4[m4][3];
            if (mt >= 8) {
                int jj0 = (mt - 8) * 8 + kq * 2;
                v0 += be1[jj0];
                v2 += be1[jj0 + 1];
            }
            ushort4 pk;
            pk.x = f2bf(v0); pk.y = f2bf(v1); pk.z = f2bf(v2); pk.w = f2bf(v3);
            if (inb) *(ushort4*)&ST[(unsigned)gr * 256u + (unsigned)stcb] = pk;
        }
    }
}

// ---------------------------------------------------------------------------
// Edge scorer (MFMA, R8/R10-proven form): wave = 16 edges. lane&15 = edge,
// rg = lane>>4 owns output cols tt*16+rg*4..+3 (node_mlp D mapping).
// Level-1 = 3 sequential uint2 loads from the 24B rec6 record; B-frag is
// pre-packed bf16 ef (no random ef gather). 8 MFMAs; z/o reduced via
// shfl_xor(16/32); 1-deep record prefetch; ST gathers issue before MFMAs.
// ---------------------------------------------------------------------------
__global__ __launch_bounds__(256)
void edge_k(const uint2* __restrict__ rec6,
            const unsigned* __restrict__ ST32, const uint4* __restrict__ efragT,
            const float* __restrict__ We2, const float* __restrict__ be2,
            const float* __restrict__ bl1, const float* __restrict__ Wl2,
            const float* __restrict__ bl2, float* __restrict__ out,
            int E, int nwaves) {
    const int l = threadIdx.x & 63;
    const int e4 = l & 15;               // edge within 16-edge group
    const int rg = l >> 4;               // row-group: cols tt*16 + rg*4 .. +3
    const int rg4 = rg << 2;
    const int wid = blockIdx.x * (blockDim.x >> 6) + (threadIdx.x >> 6);
    const int ng = (E + 15) >> 4;
    const float vbe2 = be2[0], vbl2 = bl2[0];
    const bool bzero = rg >= 2;          // B-frag zero for k >= 16
    const uint4 z4u = make_uint4(0u, 0u, 0u, 0u);
    const f32x4 zf = {0.f, 0.f, 0.f, 0.f};

    // prologue prefetch (group wid)
    unsigned srcv, eidv, dstv; uint4 bfr; bool act;
    {
        int s = wid * 16 + e4;
        act = (wid < ng) && (s < E);
        unsigned u = (act ? (unsigned)s : 0u) * 3u;
        uint2 r0 = rec6[u];
        uint2 r1 = rec6[u + 1];
        uint2 r2 = rec6[u + 2];
        srcv = r0.x; eidv = r0.y; dstv = r1.x;
        bfr = bzero ? z4u : make_uint4(r2.x, r2.y, r1.y, 0u);
    }

    for (int g = wid; g < ng; ) {
        int gn = g + nwaves;
        // prefetch next group's record
        unsigned srcn, eidn, dstn; uint4 bfn; bool actn;
        {
            int s = gn * 16 + e4;
            actn = (gn < ng) && (s < E);
            unsigned u = (actn ? (unsigned)s : 0u) * 3u;
            uint2 r0 = rec6[u];
            uint2 r1 = rec6[u + 1];
            uint2 r2 = rec6[u + 2];
            srcn = r0.x; eidn = r0.y; dstn = r1.x;
            bfn = bzero ? z4u : make_uint4(r2.x, r2.y, r1.y, 0u);
        }

        // issue all 8 ST gathers (latency hides under MFMAs below)
        unsigned srb = srcv * 128u + (unsigned)rg4;
        unsigned drb = dstv * 128u + 64u + (unsigned)rg4;
        uint4 sw0 = *(const uint4*)&ST32[srb];
        uint4 sw1 = *(const uint4*)&ST32[srb + 16u];
        uint4 sw2 = *(const uint4*)&ST32[srb + 32u];
        uint4 sw3 = *(const uint4*)&ST32[srb + 48u];
        uint4 pw0 = *(const uint4*)&ST32[drb];
        uint4 pw1 = *(const uint4*)&ST32[drb + 16u];
        uint4 pw2 = *(const uint4*)&ST32[drb + 32u];
        uint4 pw3 = *(const uint4*)&ST32[drb + 48u];

        // 8 MFMAs: D[m=out-col][n=edge]; hi/lo compensated via K-folding
        f32x4 dt0 = mfma16(efragT[0 * 64 + l], bfr, zf);
        f32x4 dt1 = mfma16(efragT[1 * 64 + l], bfr, zf);
        f32x4 dt2 = mfma16(efragT[2 * 64 + l], bfr, zf);
        f32x4 dt3 = mfma16(efragT[3 * 64 + l], bfr, zf);
        f32x4 du0 = mfma16(efragT[4 * 64 + l], bfr, zf);
        f32x4 du1 = mfma16(efragT[5 * 64 + l], bfr, zf);
        f32x4 du2 = mfma16(efragT[6 * 64 + l], bfr, zf);
        f32x4 du3 = mfma16(efragT[7 * 64 + l], bfr, zf);

        // t path: z = sum_c tanh(t_c) * We2_c   (be1 pre-folded into pw lo)
        float z = 0.f;
#define TT(i, DT, SW, PW) { \
        float4 w2v = *(const float4*)&We2[(i) * 16 + rg4]; \
        z = fmaf(fast_tanh(DT[0] + bflo(SW.x) + bflo(PW.x)), w2v.x, z); \
        z = fmaf(fast_tanh(DT[1] + bflo(SW.y) + bflo(PW.y)), w2v.y, z); \
        z = fmaf(fast_tanh(DT[2] + bflo(SW.z) + bflo(PW.z)), w2v.z, z); \
        z = fmaf(fast_tanh(DT[3] + bflo(SW.w) + bflo(PW.w)), w2v.w, z); }
        TT(0, dt0, sw0, pw0)
        TT(1, dt1, sw1, pw1)
        TT(2, dt2, sw2, pw2)
        TT(3, dt3, sw3, pw3)
#undef TT
        z += __shfl_xor(z, 16);
        z += __shfl_xor(z, 32);
        float w = fast_sigmoid(z + vbe2);

        // u path: o = sum_c relu(w*u_c + bl1_c) * Wl2_c
        float o = 0.f;
#define UT(i, DU, SW, PW) { \
        float4 blv = *(const float4*)&bl1[(i) * 16 + rg4]; \
        float4 wlv = *(const float4*)&Wl2[(i) * 16 + rg4]; \
        o = fmaf(fmaxf(fmaf(w, DU[0] + bfhi(SW.x) + bfhi(PW.x), blv.x), 0.f), wlv.x, o); \
        o = fmaf(fmaxf(fmaf(w, DU[1] + bfhi(SW.y) + bfhi(PW.y), blv.y), 0.f), wlv.y, o); \
        o = fmaf(fmaxf(fmaf(w, DU[2] + bfhi(SW.z) + bfhi(PW.z), blv.z), 0.f), wlv.z, o); \
        o = fmaf(fmaxf(fmaf(w, DU[3] + bfhi(SW.w) + bfhi(PW.w), blv.w), 0.f), wlv.w, o); }
        UT(0, du0, sw0, pw0)
        UT(1, du1, sw1, pw1)
        UT(2, du2, sw2, pw2)
        UT(3, du3, sw3, pw3)
#undef UT
        o += __shfl_xor(o, 16);
        o += __shfl_xor(o, 32);
        if (rg == 0 && act) out[eidv] = o + vbl2;

        srcv = srcn; eidv = eidn; dstv = dstn; bfr = bfn; act = actn;
        g = gn;
    }
}

extern "C" void kernel_launch(void* const* d_in, const int* in_sizes, int n_in,
                              void* d_out, int out_size, void* d_ws, size_t ws_size,
                              hipStream_t stream) {
    const float* nf  = (const float*)d_in[0];
    const float* ef  = (const float*)d_in[1];
    const int*   src = (const int*)d_in[2];
    const int*   dst = (const int*)d_in[3];
    const float* W1s = (const float*)d_in[4];
    const float* W1n = (const float*)d_in[5];
    const float* b1  = (const float*)d_in[6];
    const float* W2s = (const float*)d_in[7];
    const float* W2n = (const float*)d_in[8];
    const float* b2  = (const float*)d_in[9];
    const float* Wnp = (const float*)d_in[10];
    const float* bnp = (const float*)d_in[11];
    const float* We1 = (const float*)d_in[12];
    const float* be1 = (const float*)d_in[13];
    const float* We2 = (const float*)d_in[14];
    const float* be2 = (const float*)d_in[15];
    const float* Wl1 = (const float*)d_in[16];
    const float* bl1 = (const float*)d_in[17];
    const float* Wl2 = (const float*)d_in[18];
    const float* bl2 = (const float*)d_in[19];

    const int N = in_sizes[0] / 4;
    const int E = in_sizes[2];

    // ws layout (float units), peak ~305N + 31K floats ≈ 122.1 MB (same as
    // R10, proven):
    //  ST(bf16): [0, 128N)           written by node_mlp_mfma, read by edge_k
    //  ah1b:     [128N, 160N)        packed bf16 aggh1 (uint[32N])
    //  wfrag:    [160N, 160N+30720)  MFMA weight frags 7680 uint4 (120KB)
    //  h1b:      [160N+30720, +32N)  packed bf16 h1 (uint[32N])
    //  rec6:     [192N+30720, +96N)  uint2[3E] 24B records
    //  rank:     [288N+30720, +16N)  int[E]
    //  deg:      [304N+30720, +N)    int[N]
    //  off:      deg+N, N+1          int[N+1]
    //  bsum:     off+N+1             int[512]
    float* wsf = (float*)d_ws;
    unsigned short* ST = (unsigned short*)wsf;
    unsigned* ah1b = (unsigned*)(wsf + (size_t)128 * N);
    uint4* w2sF   = (uint4*)(wsf + (size_t)160 * N);
    uint4* w2nF   = w2sF + 1024;
    uint4* wnpF   = w2sF + 2048;
    uint4* wbigF  = w2sF + 3072;
    uint4* efragT = w2sF + 7168;   // 512 uint4 -> ends at 7680 uint4
    unsigned* h1b  = (unsigned*)(wsf + (size_t)160 * N + 30720);
    uint2* rec6 = (uint2*)(wsf + (size_t)192 * N + 30720);
    int*  rank = (int*)(wsf + (size_t)288 * N + 30720);
    int*  deg  = (int*)(wsf + (size_t)304 * N + 30720);
    int*  off  = deg + N;
    int*  bsum = off + N + 1;
    float* out = (float*)d_out;

    const int nblkN1 = (N + 255) / 256;
    const int nblkE  = (E + 255) / 256;
    const int nblkNw4 = (N + 3) / 4;      // 256-thread, 4 nodes (gatherh1)
    const int nblkN16 = (N + 15) / 16;    // 256-thread, 16 nodes (aggh1f)
    const int gemmx  = (N + 63) / 64;
    const int EDGE_BLOCKS = 3072;
    const int nwaves = EDGE_BLOCKS * 4;

    // weight frag prep (depends only on inputs; run first)
    prep_w_k<<<5, 256, 0, stream>>>(W2s, W2n, Wnp, We1, Wl1,
                                    w2sF, w2nF, wnpF, wbigF, efragT);

    // CSR build: single atomic pass (rank) + scan + atomic-free 24B fill
    hipMemsetAsync(deg, 0, (size_t)N * sizeof(int), stream);
    rank_k<<<nblkE, 256, 0, stream>>>(dst, deg, rank, E);
    scan1_k<<<nblkN1, 256, 0, stream>>>(deg, off, bsum, N);
    scan2_k<<<1, 512, 0, stream>>>(bsum, nblkN1);
    scan3_k<<<nblkN1, 256, 0, stream>>>(off, bsum, N, E);
    fill2_k<<<nblkE, 256, 0, stream>>>(src, dst, off, rank, ef, rec6, E);

    // layer 1 (fused aggregate + h1, bf16 out; quarter-wave per node)
    aggh1f_k<<<nblkN16, 256, 0, stream>>>(off, rec6, nf, W1s, W1n, b1, h1b, N);

    // layer 2 gather (bf16 out, uint4, 16 rows in flight, index prefetch)
    gatherh1_k<<<nblkNw4, 256, 0, stream>>>(off, rec6, (const uint4*)h1b,
                                            (uint4*)ah1b, N);

    // fused node MLP on matrix cores -> bf16 ST table
    node_mlp_mfma_k<<<gemmx, 256, 0, stream>>>((const uint4*)h1b, (const uint4*)ah1b,
                                               w2sF, w2nF, wnpF, wbigF,
                                               b2, bnp, be1, ST, N);

    // per-edge scoring (MFMA ef-offload, single 24B record stream)
    edge_k<<<EDGE_BLOCKS, 256, 0, stream>>>(rec6, (const unsigned*)ST,
                                            efragT, We2, be2, bl1, Wl2, bl2,
                                            out, E, nwaves);
}

// Round 12
// 453.460 us; speedup vs baseline: 1.0357x; 1.0163x over previous
//
#include <hip/hip_runtime.h>
#include <math.h>

// ---------------------------------------------------------------------------
// EdgeClassifier: 2x SAGEConv(mean) -> per-node MLP -> edge scorer
//  * layer-1 agg: mean commutes with projection -> aggregate raw nf (4-dim),
//    fused with h1 compute; quarter-wave (16 lanes) per node, DPP all-reduce
//  * CSR: R4/R8-proven build: rank_k (atomic returning rank) + scan +
//    atomic-free fill2_k scatter into slot4 {src, eid, dst, 0}.
//  * gatherh1/aggh1f: 1-deep slot-index prefetch
//  * node_mlp_mfma_k: MFMA (16x16x32 bf16) node MLP; weights pre-split
//    hi/lo bf16 (prep_w_k); swapped operands -> direct ushort4 ST stores.
//  * edge_k: EXACT R8 MFMA form + T1 XCD-chunked block swizzle (NEW):
//    slots are dst-sorted, so adjacent groups share dst ST rows; default
//    round-robin block->XCD dispatch replicates those lines across 8
//    per-XCD L2s. Chunked swizzle (bijective, 3072%8==0) gives each XCD a
//    contiguous slot range -> dst/stream lines cached once per XCD.
//    EVIDENCE LEDGER: edge_k is FETCH-bound (R4=R8=R9 at 131-133us; R10
//    byte-cut moved it). ef-prepack ladder (R10/R11) RETIRED: edge -28us
//    but tail +40us, net loss vs R8's 449. R9 deep pipeline RETIRED
//    (null). Packed-f2 RETIRED (R3/R5 spills). R6 atomic fill RETIRED.
//    TRIPWIRES: WRITE>60MB = spill -> revert; absmax != 4.882812e-4 ->
//    bug -> revert; edge_k dur 131+-3 -> swizzle null -> declare plateau.
// ---------------------------------------------------------------------------

typedef __attribute__((ext_vector_type(8))) short bf16x8;
typedef __attribute__((ext_vector_type(4))) float f32x4;

__device__ __forceinline__ float fast_tanh(float x) {
    x = fminf(fmaxf(x, -15.f), 15.f);
    float e2 = __expf(2.f * x);
    return (e2 - 1.f) * __builtin_amdgcn_rcpf(e2 + 1.f);
}
__device__ __forceinline__ float fast_sigmoid(float x) {
    x = fminf(fmaxf(x, -60.f), 60.f);
    return __builtin_amdgcn_rcpf(1.f + __expf(-x));
}
__device__ __forceinline__ unsigned short f2bf(float f) {   // RNE
    unsigned u = __float_as_uint(f);
    u = u + 0x7FFFu + ((u >> 16) & 1u);
    return (unsigned short)(u >> 16);
}
__device__ __forceinline__ unsigned pack2bf(float lo, float hi) {
    return ((unsigned)f2bf(hi) << 16) | (unsigned)f2bf(lo);
}
__device__ __forceinline__ float bflo(unsigned u) { return __uint_as_float(u << 16); }
__device__ __forceinline__ float bfhi(unsigned u) { return __uint_as_float(u & 0xFFFF0000u); }
__device__ __forceinline__ float bf2f(unsigned short h) {
    return __uint_as_float((unsigned)h << 16);
}

__device__ __forceinline__ f32x4 mfma16(uint4 a, uint4 b, f32x4 c) {
    return __builtin_amdgcn_mfma_f32_16x16x32_bf16(
        __builtin_bit_cast(bf16x8, a), __builtin_bit_cast(bf16x8, b), c, 0, 0, 0);
}

// 16-lane all-reduce sum, pure DPP (no LDS/DS); reduces within 16-lane rows
__device__ __forceinline__ float dpp_sum16(float x) {
    int t;
    t = __builtin_amdgcn_update_dpp(0, __float_as_int(x), 0xB1, 0xF, 0xF, true);  // quad_perm(1,0,3,2)
    x += __int_as_float(t);
    t = __builtin_amdgcn_update_dpp(0, __float_as_int(x), 0x4E, 0xF, 0xF, true);  // quad_perm(2,3,0,1)
    x += __int_as_float(t);
    t = __builtin_amdgcn_update_dpp(0, __float_as_int(x), 0x141, 0xF, 0xF, true); // row_half_mirror
    x += __int_as_float(t);
    t = __builtin_amdgcn_update_dpp(0, __float_as_int(x), 0x140, 0xF, 0xF, true); // row_mirror
    x += __int_as_float(t);
    return x;
}

// rank[e] = arrival index among edges sharing dst; deg accumulates counts
__global__ void rank_k(const int* __restrict__ dst, int* __restrict__ deg,
                       int* __restrict__ rank, int E) {
    int e = blockIdx.x * blockDim.x + threadIdx.x;
    if (e < E) rank[e] = atomicAdd(&deg[dst[e]], 1);
}

__global__ void scan1_k(const int* __restrict__ deg, int* __restrict__ off,
                        int* __restrict__ bsum, int N) {
    __shared__ int tmp[256];
    int i = blockIdx.x * 256 + threadIdx.x;
    int v = (i < N) ? deg[i] : 0;
    tmp[threadIdx.x] = v;
    __syncthreads();
#pragma unroll
    for (int s = 1; s < 256; s <<= 1) {
        int t = (threadIdx.x >= s) ? tmp[threadIdx.x - s] : 0;
        __syncthreads();
        tmp[threadIdx.x] += t;
        __syncthreads();
    }
    if (i < N) off[i] = tmp[threadIdx.x] - v;
    if (threadIdx.x == 255) bsum[blockIdx.x] = tmp[255];
}

__global__ void scan2_k(int* __restrict__ bsum, int nb) {
    __shared__ int tmp[512];
    int i = threadIdx.x;
    int v = (i < nb) ? bsum[i] : 0;
    tmp[i] = v;
    __syncthreads();
#pragma unroll
    for (int s = 1; s < 512; s <<= 1) {
        int t = (i >= s) ? tmp[i - s] : 0;
        __syncthreads();
        tmp[i] += t;
        __syncthreads();
    }
    if (i < nb) bsum[i] = tmp[i] - v;
}

__global__ void scan3_k(int* __restrict__ off, const int* __restrict__ bsum,
                        int N, int E) {
    int i = blockIdx.x * 256 + threadIdx.x;
    if (i < N) off[i] += bsum[blockIdx.x];
    if (i == 0) off[N] = E;
}

// atomic-free CSR fill: single 16B scatter per edge {src, eid, dst, 0}
__global__ void fill2_k(const int* __restrict__ src, const int* __restrict__ dst,
                        const int* __restrict__ off, const int* __restrict__ rank,
                        int4* __restrict__ slot4, int E) {
    int e = blockIdx.x * blockDim.x + threadIdx.x;
    if (e >= E) return;
    int d = dst[e];
    int pos = off[d] + rank[e];
    slot4[pos] = make_int4(src[e], e, d, 0);
}

// ---------------------------------------------------------------------------
// Weight prep (runs once): MFMA fragment-layout hi/lo bf16 copies, plus
// edge A-frag table efragT[8][64]: tiles 0..3 = We1 rows 128..132 (t path),
// tiles 4..7 = Wl1 rows 128..132 (u path). kq==0 lanes carry hi bf16 at
// k=0..4; kq==1 lanes carry lo residual at k=8..12 (hi/lo-in-K trick:
// B duplicates ef in both k ranges, one MFMA sums both products).
// ---------------------------------------------------------------------------
__global__ void prep_w_k(const float* __restrict__ W2s, const float* __restrict__ W2n,
                         const float* __restrict__ Wnp, const float* __restrict__ We1,
                         const float* __restrict__ Wl1, uint4* __restrict__ w2sF,
                         uint4* __restrict__ w2nF, uint4* __restrict__ wnpF,
                         uint4* __restrict__ wbigF, uint4* __restrict__ efragT) {
    const int b = blockIdx.x, t = threadIdx.x;
    if (b < 3) {
        const float* W = (b == 0) ? W2s : (b == 1) ? W2n : Wnp;
        uint4* out = (b == 0) ? w2sF : (b == 1) ? w2nF : wnpF;
        for (int u = t; u < 2 * 4 * 64; u += 256) {
            int l = u & 63, nt = (u >> 6) & 3, ks = u >> 8;
            int m = nt * 16 + (l & 15), kb = ks * 32 + (l >> 4) * 8;
            unsigned hi[4], lo[4];
#pragma unroll
            for (int jp = 0; jp < 4; ++jp) {
                float v0 = W[(kb + 2 * jp) * 64 + m];
                float v1 = W[(kb + 2 * jp + 1) * 64 + m];
                unsigned short h0 = f2bf(v0), h1 = f2bf(v1);
                unsigned short q0 = f2bf(v0 - bf2f(h0)), q1 = f2bf(v1 - bf2f(h1));
                hi[jp] = ((unsigned)h1 << 16) | h0;
                lo[jp] = ((unsigned)q1 << 16) | q0;
            }
            out[u * 2]     = make_uint4(hi[0], hi[1], hi[2], hi[3]);
            out[u * 2 + 1] = make_uint4(lo[0], lo[1], lo[2], lo[3]);
        }
    } else if (b == 3) {
        for (int u = t; u < 2 * 16 * 64; u += 256) {
            int l = u & 63, nt = (u >> 6) & 15, ks = u >> 10;
            int m = nt * 16 + (l & 15), kb = ks * 32 + (l >> 4) * 8;
            int half = m >> 7, cc = m & 127, jj = cc >> 1, p = cc & 1;
            const float* W = p ? Wl1 : We1;
            unsigned hi[4], lo[4];
#pragma unroll
            for (int jp = 0; jp < 4; ++jp) {
                float v0 = W[(half * 64 + kb + 2 * jp) * 64 + jj];
                float v1 = W[(half * 64 + kb + 2 * jp + 1) * 64 + jj];
                unsigned short h0 = f2bf(v0), h1 = f2bf(v1);
                unsigned short q0 = f2bf(v0 - bf2f(h0)), q1 = f2bf(v1 - bf2f(h1));
                hi[jp] = ((unsigned)h1 << 16) | h0;
                lo[jp] = ((unsigned)q1 << 16) | q0;
            }
            wbigF[u * 2]     = make_uint4(hi[0], hi[1], hi[2], hi[3]);
            wbigF[u * 2 + 1] = make_uint4(lo[0], lo[1], lo[2], lo[3]);
        }
    } else {
        for (int u = t; u < 8 * 64; u += 256) {
            int l = u & 63, tile = u >> 6;
            int kq = l >> 4, m16 = l & 15;
            const float* W = (tile < 4) ? We1 : Wl1;
            int c = (tile & 3) * 16 + m16;
            unsigned uu0 = 0u, uu1 = 0u, uu2 = 0u;
            if (kq < 2) {
                float v[5];
#pragma unroll
                for (int j = 0; j < 5; ++j) {
                    float wv = W[(128 + j) * 64 + c];
                    unsigned short h = f2bf(wv);
                    v[j] = (kq == 0) ? bf2f(h) : (wv - bf2f(h));
                }
                uu0 = pack2bf(v[0], v[1]);
                uu1 = pack2bf(v[2], v[3]);
                uu2 = pack2bf(v[4], 0.f);
            }
            efragT[tile * 64 + l] = make_uint4(uu0, uu1, uu2, 0u);
        }
    }
}

// quarter-wave (16 lanes) per node, 16 nodes/block: aggnf = mean of
// nf[neighbors] (stride-16 gather + DPP-16 all-reduce, 1-deep index
// prefetch), then lane q computes h1 cols 4q..4q+3, packed bf16.
__global__ __launch_bounds__(256, 8)
void aggh1f_k(const int* __restrict__ off, const int4* __restrict__ slot4,
              const float* __restrict__ nf,
              const float* __restrict__ W1s, const float* __restrict__ W1n,
              const float* __restrict__ b1, unsigned* __restrict__ h1b, int N) {
    int n = blockIdx.x * 16 + (threadIdx.x >> 4);
    if (n >= N) return;
    int q = threadIdx.x & 15;
    int s0 = off[n], s1 = off[n + 1];
    const float4* nf4 = (const float4*)nf;
    float4 a = {0.f, 0.f, 0.f, 0.f};
    int i = s0 + q;
    int nx = (i < s1) ? slot4[i].x : 0;
    for (; i < s1; ) {
        int cur = nx;
        int in = i + 16;
        if (in < s1) nx = slot4[in].x;       // prefetch next index
        float4 r = nf4[(unsigned)cur];
        a.x += r.x; a.y += r.y; a.z += r.z; a.w += r.w;
        i = in;
    }
    a.x = dpp_sum16(a.x);
    a.y = dpp_sum16(a.y);
    a.z = dpp_sum16(a.z);
    a.w = dpp_sum16(a.w);
    float invd = 1.f / fmaxf((float)(s1 - s0), 1.f);
    a.x *= invd; a.y *= invd; a.z *= invd; a.w *= invd;
    float4 r = nf4[(unsigned)n];
    const int j0 = q << 2;
    float4 acc = *(const float4*)&b1[j0];
#pragma unroll
    for (int k = 0; k < 4; ++k) {
        float rk = (k == 0) ? r.x : (k == 1) ? r.y : (k == 2) ? r.z : r.w;
        float ak = (k == 0) ? a.x : (k == 1) ? a.y : (k == 2) ? a.z : a.w;
        float4 ws = *(const float4*)&W1s[k * 64 + j0];
        float4 wn = *(const float4*)&W1n[k * 64 + j0];
        acc.x = fmaf(rk, ws.x, acc.x); acc.y = fmaf(rk, ws.y, acc.y);
        acc.z = fmaf(rk, ws.z, acc.z); acc.w = fmaf(rk, ws.w, acc.w);
        acc.x = fmaf(ak, wn.x, acc.x); acc.y = fmaf(ak, wn.y, acc.y);
        acc.z = fmaf(ak, wn.z, acc.z); acc.w = fmaf(ak, wn.w, acc.w);
    }
    uint2 pk;
    pk.x = pack2bf(fmaxf(acc.x, 0.f), fmaxf(acc.y, 0.f));
    pk.y = pack2bf(fmaxf(acc.z, 0.f), fmaxf(acc.w, 0.f));
    *(uint2*)&h1b[(unsigned)n * 32u + (q << 1)] = pk;
}

// one wave per node (4 nodes/block): aggh1b[n] = mean of bf16 h1 rows.
// 16 rows in flight; next iteration's slot indices prefetched.
__global__ __launch_bounds__(256, 8)
void gatherh1_k(const int* __restrict__ off, const int4* __restrict__ slot4,
                const uint4* __restrict__ h1b4, uint4* __restrict__ ah1b4, int N) {
    int n = blockIdx.x * 4 + (threadIdx.x >> 6);
    if (n >= N) return;
    int l = threadIdx.x & 63;
    int g = l >> 3, q = l & 7;
    int s0 = off[n], s1 = off[n + 1];
    float a0 = 0.f, a1 = 0.f, a2 = 0.f, a3 = 0.f;
    float a4 = 0.f, a5 = 0.f, a6 = 0.f, a7 = 0.f;
    int i = s0;
    int nA = 0, nB = 0;
    if (i + 16 <= s1) { nA = slot4[i + g].x; nB = slot4[i + 8 + g].x; }
    for (; i + 16 <= s1; ) {
        int cA = nA, cB = nB;
        int in = i + 16;
        if (in + 16 <= s1) {
            nA = slot4[in + g].x;
            nB = slot4[in + 8 + g].x;
        }
        uint4 v0 = h1b4[(unsigned)cA * 8u + q];
        uint4 v1 = h1b4[(unsigned)cB * 8u + q];
        a0 += bflo(v0.x) + bflo(v1.x); a1 += bfhi(v0.x) + bfhi(v1.x);
        a2 += bflo(v0.y) + bflo(v1.y); a3 += bfhi(v0.y) + bfhi(v1.y);
        a4 += bflo(v0.z) + bflo(v1.z); a5 += bfhi(v0.z) + bfhi(v1.z);
        a6 += bflo(v0.w) + bflo(v1.w); a7 += bfhi(v0.w) + bfhi(v1.w);
        i = in;
    }
    for (; i + 8 <= s1; i += 8) {
        int r = slot4[i + g].x;
        uint4 v = h1b4[(unsigned)r * 8u + q];
        a0 += bflo(v.x); a1 += bfhi(v.x);
        a2 += bflo(v.y); a3 += bfhi(v.y);
        a4 += bflo(v.z); a5 += bfhi(v.z);
        a6 += bflo(v.w); a7 += bfhi(v.w);
    }
    int rem = s1 - i;
    if (g < rem) {
        int r = slot4[i + g].x;
        uint4 v = h1b4[(unsigned)r * 8u + q];
        a0 += bflo(v.x); a1 += bfhi(v.x);
        a2 += bflo(v.y); a3 += bfhi(v.y);
        a4 += bflo(v.z); a5 += bfhi(v.z);
        a6 += bflo(v.w); a7 += bfhi(v.w);
    }
#pragma unroll
    for (int m = 8; m <= 32; m <<= 1) {
        a0 += __shfl_xor(a0, m); a1 += __shfl_xor(a1, m);
        a2 += __shfl_xor(a2, m); a3 += __shfl_xor(a3, m);
        a4 += __shfl_xor(a4, m); a5 += __shfl_xor(a5, m);
        a6 += __shfl_xor(a6, m); a7 += __shfl_xor(a7, m);
    }
    if (l < 8) {
        float invd = 1.f / fmaxf((float)(s1 - s0), 1.f);
        uint4 pk;
        pk.x = pack2bf(a0 * invd, a1 * invd);
        pk.y = pack2bf(a2 * invd, a3 * invd);
        pk.z = pack2bf(a4 * invd, a5 * invd);
        pk.w = pack2bf(a6 * invd, a7 * invd);
        ah1b4[(unsigned)n * 8u + q] = pk;
    }
}

// ---------------------------------------------------------------------------
// MFMA node MLP (unchanged; verified absmax-identical).
// ---------------------------------------------------------------------------
__global__ __launch_bounds__(256)
void node_mlp_mfma_k(const uint4* __restrict__ h1v, const uint4* __restrict__ ahv,
                     const uint4* __restrict__ w2sF, const uint4* __restrict__ w2nF,
                     const uint4* __restrict__ wnpF, const uint4* __restrict__ wbigF,
                     const float* __restrict__ b2, const float* __restrict__ bnp,
                     const float* __restrict__ be1, unsigned short* __restrict__ ST,
                     int N) {
    __shared__ __align__(16) unsigned short Ahi[64][72];
    __shared__ __align__(16) unsigned short Alo[64][72];
    const int t = threadIdx.x;
    const int w = t >> 6, l = t & 63;
    const int lr = l & 15, kq = l >> 4;
    const int m0 = blockIdx.x * 64;
    const int gr = m0 + w * 16 + lr;
    const bool inb = gr < N;
    const int prow = w * 16 + lr;
    const int cbq = kq * 4;

    const uint4 z4 = make_uint4(0u, 0u, 0u, 0u);

    uint4 x1[2], xa[2];
#pragma unroll
    for (int ks = 0; ks < 2; ++ks) {
        unsigned idx = (unsigned)gr * 8u + (unsigned)(ks * 4 + kq);
        x1[ks] = inb ? h1v[idx] : z4;
        xa[ks] = inb ? ahv[idx] : z4;
    }

    // ---- layer 2: h2 = relu(X1@W2s + Xa@W2n + b2) ----
    f32x4 acc[4];
#pragma unroll
    for (int nt = 0; nt < 4; ++nt) acc[nt] = (f32x4){0.f, 0.f, 0.f, 0.f};
#pragma unroll
    for (int ks = 0; ks < 2; ++ks)
#pragma unroll
        for (int nt = 0; nt < 4; ++nt) {
            int base = ((ks * 4 + nt) * 64 + l) * 2;
            acc[nt] = mfma16(w2sF[base],     x1[ks], acc[nt]);
            acc[nt] = mfma16(w2sF[base + 1], x1[ks], acc[nt]);
            acc[nt] = mfma16(w2nF[base],     xa[ks], acc[nt]);
            acc[nt] = mfma16(w2nF[base + 1], xa[ks], acc[nt]);
        }
#pragma unroll
    for (int nt = 0; nt < 4; ++nt) {
        float4 vb = *(const float4*)&b2[nt * 16 + cbq];
        float v0 = fmaxf(acc[nt][0] + vb.x, 0.f);
        float v1 = fmaxf(acc[nt][1] + vb.y, 0.f);
        float v2 = fmaxf(acc[nt][2] + vb.z, 0.f);
        float v3 = fmaxf(acc[nt][3] + vb.w, 0.f);
        unsigned short h0 = f2bf(v0), h1 = f2bf(v1), h2 = f2bf(v2), h3 = f2bf(v3);
        unsigned short q0 = f2bf(v0 - bf2f(h0)), q1 = f2bf(v1 - bf2f(h1));
        unsigned short q2 = f2bf(v2 - bf2f(h2)), q3 = f2bf(v3 - bf2f(h3));
        *(uint2*)&Ahi[prow][nt * 16 + cbq] =
            make_uint2(((unsigned)h1 << 16) | h0, ((unsigned)h3 << 16) | h2);
        *(uint2*)&Alo[prow][nt * 16 + cbq] =
            make_uint2(((unsigned)q1 << 16) | q0, ((unsigned)q3 << 16) | q2);
    }
    __syncthreads();

    uint4 ahi2[2], alo2[2];
#pragma unroll
    for (int ks = 0; ks < 2; ++ks) {
        ahi2[ks] = *(const uint4*)&Ahi[prow][ks * 32 + kq * 8];
        alo2[ks] = *(const uint4*)&Alo[prow][ks * 32 + kq * 8];
    }

    // ---- layer 3: hn = relu(h2@Wnp + bnp) ----
    f32x4 a3[4];
#pragma unroll
    for (int nt = 0; nt < 4; ++nt) a3[nt] = (f32x4){0.f, 0.f, 0.f, 0.f};
#pragma unroll
    for (int ks = 0; ks < 2; ++ks)
#pragma unroll
        for (int nt = 0; nt < 4; ++nt) {
            int base = ((ks * 4 + nt) * 64 + l) * 2;
            a3[nt] = mfma16(wnpF[base],     ahi2[ks], a3[nt]);
            a3[nt] = mfma16(wnpF[base + 1], ahi2[ks], a3[nt]);
            a3[nt] = mfma16(wnpF[base],     alo2[ks], a3[nt]);
        }
#pragma unroll
    for (int nt = 0; nt < 4; ++nt) {
        float4 vb = *(const float4*)&bnp[nt * 16 + cbq];
        float v0 = fmaxf(a3[nt][0] + vb.x, 0.f);
        float v1 = fmaxf(a3[nt][1] + vb.y, 0.f);
        float v2 = fmaxf(a3[nt][2] + vb.z, 0.f);
        float v3 = fmaxf(a3[nt][3] + vb.w, 0.f);
        unsigned short h0 = f2bf(v0), h1 = f2bf(v1), h2 = f2bf(v2), h3 = f2bf(v3);
        unsigned short q0 = f2bf(v0 - bf2f(h0)), q1 = f2bf(v1 - bf2f(h1));
        unsigned short q2 = f2bf(v2 - bf2f(h2)), q3 = f2bf(v3 - bf2f(h3));
        *(uint2*)&Ahi[prow][nt * 16 + cbq] =
            make_uint2(((unsigned)h1 << 16) | h0, ((unsigned)h3 << 16) | h2);
        *(uint2*)&Alo[prow][nt * 16 + cbq] =
            make_uint2(((unsigned)q1 << 16) | q0, ((unsigned)q3 << 16) | q2);
    }
    __syncthreads();

    uint4 bhi[2], blo[2];
#pragma unroll
    for (int ks = 0; ks < 2; ++ks) {
        bhi[ks] = *(const uint4*)&Ahi[prow][ks * 32 + kq * 8];
        blo[ks] = *(const uint4*)&Alo[prow][ks * 32 + kq * 8];
    }

    // ---- layer 4: ST = hn @ Wbig, 16 col-tiles, direct ushort4 stores ----
#pragma unroll
    for (int mtg = 0; mtg < 4; ++mtg) {
        f32x4 a4[4];
#pragma unroll
        for (int m4 = 0; m4 < 4; ++m4) a4[m4] = (f32x4){0.f, 0.f, 0.f, 0.f};
#pragma unroll
        for (int m4 = 0; m4 < 4; ++m4) {
            int mt = mtg * 4 + m4;
#pragma unroll
            for (int ks = 0; ks < 2; ++ks) {
                int base = ((ks * 16 + mt) * 64 + l) * 2;
                a4[m4] = mfma16(wbigF[base],     bhi[ks], a4[m4]);
                a4[m4] = mfma16(wbigF[base + 1], bhi[ks], a4[m4]);
                a4[m4] = mfma16(wbigF[base],     blo[ks], a4[m4]);
            }
        }
#pragma unroll
        for (int m4 = 0; m4 < 4; ++m4) {
            int mt = mtg * 4 + m4;
            int stcb = mt * 16 + cbq;
            float v0 = a4[m4][0], v1 = a4[m4][1], v2 = a4[m4][2], v3 = a4[m4][3];
            if (mt >= 8) {
                int jj0 = (mt - 8) * 8 + kq * 2;
                v0 += be1[jj0];
                v2 += be1[jj0 + 1];
            }
            ushort4 pk;
            pk.x = f2bf(v0); pk.y = f2bf(v1); pk.z = f2bf(v2); pk.w = f2bf(v3);
            if (inb) *(ushort4*)&ST[(unsigned)gr * 256u + (unsigned)stcb] = pk;
        }
    }
}

// ---------------------------------------------------------------------------
// Edge scorer (MFMA, R8 form + T1 XCD-chunked block swizzle): wave = 16
// edges. lane&15 = edge, rg = lane>>4 owns output cols tt*16+rg*4..+3.
// Swizzle sbid=(bid&7)*(nblk/8)+(bid>>3) gives each XCD a contiguous slot
// range -> dst-half ST lines (dst-sorted slots) cached once per XCD L2
// instead of replicated across all 8. Arithmetic identical to R8.
// ---------------------------------------------------------------------------
__global__ __launch_bounds__(256)
void edge_k(const int4* __restrict__ slot4, const float* __restrict__ ef,
            const unsigned* __restrict__ ST32, const uint4* __restrict__ efragT,
            const float* __restrict__ We2, const float* __restrict__ be2,
            const float* __restrict__ bl1, const float* __restrict__ Wl2,
            const float* __restrict__ bl2, float* __restrict__ out,
            int E, int nwaves) {
    const int l = threadIdx.x & 63;
    const int e4 = l & 15;               // edge within 16-edge group
    const int rg = l >> 4;               // row-group: cols tt*16 + rg*4 .. +3
    const int rg4 = rg << 2;
    // T1 XCD-chunked swizzle (bijective: gridDim.x % 8 == 0)
    const int cpx = (int)(gridDim.x >> 3);
    const int sbid = ((int)blockIdx.x & 7) * cpx + ((int)blockIdx.x >> 3);
    const int wid = sbid * (blockDim.x >> 6) + (threadIdx.x >> 6);
    const int ng = (E + 15) >> 4;
    const float vbe2 = be2[0], vbl2 = bl2[0];
    const bool bzero = rg >= 2;          // B-frag zero for k >= 16
    const uint4 z4u = make_uint4(0u, 0u, 0u, 0u);
    const f32x4 zf = {0.f, 0.f, 0.f, 0.f};

    // prologue prefetch (group wid)
    int4 sv; uint4 bfr; bool act;
    {
        int s = wid * 16 + e4;
        act = (wid < ng) && (s < E);
        sv = slot4[act ? (unsigned)s : 0u];
        const float* ep = ef + (unsigned)sv.y * 5u;
        unsigned b0 = pack2bf(ep[0], ep[1]);
        unsigned b1 = pack2bf(ep[2], ep[3]);
        unsigned b2 = pack2bf(ep[4], 0.f);
        bfr = bzero ? z4u : make_uint4(b0, b1, b2, 0u);
    }

    for (int g = wid; g < ng; ) {
        int gn = g + nwaves;
        // prefetch next group's slot4 + ef->B-frag
        int4 svn; uint4 bfn; bool actn;
        {
            int s = gn * 16 + e4;
            actn = (gn < ng) && (s < E);
            svn = slot4[actn ? (unsigned)s : 0u];
            const float* ep = ef + (unsigned)svn.y * 5u;
            unsigned b0 = pack2bf(ep[0], ep[1]);
            unsigned b1 = pack2bf(ep[2], ep[3]);
            unsigned b2 = pack2bf(ep[4], 0.f);
            bfn = bzero ? z4u : make_uint4(b0, b1, b2, 0u);
        }

        // issue all 8 ST gathers (latency hides under MFMAs below)
        unsigned srb = (unsigned)sv.x * 128u + (unsigned)rg4;
        unsigned drb = (unsigned)sv.z * 128u + 64u + (unsigned)rg4;
        uint4 sw0 = *(const uint4*)&ST32[srb];
        uint4 sw1 = *(const uint4*)&ST32[srb + 16u];
        uint4 sw2 = *(const uint4*)&ST32[srb + 32u];
        uint4 sw3 = *(const uint4*)&ST32[srb + 48u];
        uint4 pw0 = *(const uint4*)&ST32[drb];
        uint4 pw1 = *(const uint4*)&ST32[drb + 16u];
        uint4 pw2 = *(const uint4*)&ST32[drb + 32u];
        uint4 pw3 = *(const uint4*)&ST32[drb + 48u];

        // 8 MFMAs: D[m=out-col][n=edge]; hi/lo compensated via K-folding
        f32x4 dt0 = mfma16(efragT[0 * 64 + l], bfr, zf);
        f32x4 dt1 = mfma16(efragT[1 * 64 + l], bfr, zf);
        f32x4 dt2 = mfma16(efragT[2 * 64 + l], bfr, zf);
        f32x4 dt3 = mfma16(efragT[3 * 64 + l], bfr, zf);
        f32x4 du0 = mfma16(efragT[4 * 64 + l], bfr, zf);
        f32x4 du1 = mfma16(efragT[5 * 64 + l], bfr, zf);
        f32x4 du2 = mfma16(efragT[6 * 64 + l], bfr, zf);
        f32x4 du3 = mfma16(efragT[7 * 64 + l], bfr, zf);

        // t path: z = sum_c tanh(t_c) * We2_c   (be1 pre-folded into pw lo)
        float z = 0.f;
#define TT(i, DT, SW, PW) { \
        float4 w2v = *(const float4*)&We2[(i) * 16 + rg4]; \
        z = fmaf(fast_tanh(DT[0] + bflo(SW.x) + bflo(PW.x)), w2v.x, z); \
        z = fmaf(fast_tanh(DT[1] + bflo(SW.y) + bflo(PW.y)), w2v.y, z); \
        z = fmaf(fast_tanh(DT[2] + bflo(SW.z) + bflo(PW.z)), w2v.z, z); \
        z = fmaf(fast_tanh(DT[3] + bflo(SW.w) + bflo(PW.w)), w2v.w, z); }
        TT(0, dt0, sw0, pw0)
        TT(1, dt1, sw1, pw1)
        TT(2, dt2, sw2, pw2)
        TT(3, dt3, sw3, pw3)
#undef TT
        z += __shfl_xor(z, 16);
        z += __shfl_xor(z, 32);
        float w = fast_sigmoid(z + vbe2);

        // u path: o = sum_c relu(w*u_c + bl1_c) * Wl2_c
        float o = 0.f;
#define UT(i, DU, SW, PW) { \
        float4 blv = *(const float4*)&bl1[(i) * 16 + rg4]; \
        float4 wlv = *(const float4*)&Wl2[(i) * 16 + rg4]; \
        o = fmaf(fmaxf(fmaf(w, DU[0] + bfhi(SW.x) + bfhi(PW.x), blv.x), 0.f), wlv.x, o); \
        o = fmaf(fmaxf(fmaf(w, DU[1] + bfhi(SW.y) + bfhi(PW.y), blv.y), 0.f), wlv.y, o); \
        o = fmaf(fmaxf(fmaf(w, DU[2] + bfhi(SW.z) + bfhi(PW.z), blv.z), 0.f), wlv.z, o); \
        o = fmaf(fmaxf(fmaf(w, DU[3] + bfhi(SW.w) + bfhi(PW.w), blv.w), 0.f), wlv.w, o); }
        UT(0, du0, sw0, pw0)
        UT(1, du1, sw1, pw1)
        UT(2, du2, sw2, pw2)
        UT(3, du3, sw3, pw3)
#undef UT
        o += __shfl_xor(o, 16);
        o += __shfl_xor(o, 32);
        if (rg == 0 && act) out[(unsigned)sv.y] = o + vbl2;

        sv = svn; bfr = bfn; act = actn;
        g = gn;
    }
}

extern "C" void kernel_launch(void* const* d_in, const int* in_sizes, int n_in,
                              void* d_out, int out_size, void* d_ws, size_t ws_size,
                              hipStream_t stream) {
    const float* nf  = (const float*)d_in[0];
    const float* ef  = (const float*)d_in[1];
    const int*   src = (const int*)d_in[2];
    const int*   dst = (const int*)d_in[3];
    const float* W1s = (const float*)d_in[4];
    const float* W1n = (const float*)d_in[5];
    const float* b1  = (const float*)d_in[6];
    const float* W2s = (const float*)d_in[7];
    const float* W2n = (const float*)d_in[8];
    const float* b2  = (const float*)d_in[9];
    const float* Wnp = (const float*)d_in[10];
    const float* bnp = (const float*)d_in[11];
    const float* We1 = (const float*)d_in[12];
    const float* be1 = (const float*)d_in[13];
    const float* We2 = (const float*)d_in[14];
    const float* be2 = (const float*)d_in[15];
    const float* Wl1 = (const float*)d_in[16];
    const float* bl1 = (const float*)d_in[17];
    const float* Wl2 = (const float*)d_in[18];
    const float* bl2 = (const float*)d_in[19];

    const int N = in_sizes[0] / 4;
    const int E = in_sizes[2];

    // ws layout (float units), peak ~273N + 31K floats ≈ 109.4 MB (R8-proven):
    //  ST(bf16): [0, 128N)           written by node_mlp_mfma, read by edge_k
    //  ah1b:     [128N, 160N)        packed bf16 aggh1 (uint[32N])
    //  wfrag:    [160N, 160N+30720)  MFMA weight frags 7680 uint4 (120KB)
    //  h1b:      [160N+30720, +32N)  packed bf16 h1 (uint[32N])
    //  slot4:    [192N+30720, +64N)  int4[E] {src, eid, dst, 0}
    //  rank:     [256N+30720, +16N)  int[E]
    //  deg:      [272N+30720, +N)    int[N]
    //  off:      deg+N, N+1          int[N+1]
    //  bsum:     off+N+1             int[512]
    float* wsf = (float*)d_ws;
    unsigned short* ST = (unsigned short*)wsf;
    unsigned* ah1b = (unsigned*)(wsf + (size_t)128 * N);
    uint4* w2sF   = (uint4*)(wsf + (size_t)160 * N);
    uint4* w2nF   = w2sF + 1024;
    uint4* wnpF   = w2sF + 2048;
    uint4* wbigF  = w2sF + 3072;
    uint4* efragT = w2sF + 7168;   // 512 uint4 -> ends at 7680 uint4
    unsigned* h1b  = (unsigned*)(wsf + (size_t)160 * N + 30720);
    int4* slot4 = (int4*)(wsf + (size_t)192 * N + 30720);
    int*  rank = (int*)(wsf + (size_t)256 * N + 30720);
    int*  deg  = (int*)(wsf + (size_t)272 * N + 30720);
    int*  off  = deg + N;
    int*  bsum = off + N + 1;
    float* out = (float*)d_out;

    const int nblkN1 = (N + 255) / 256;
    const int nblkE  = (E + 255) / 256;
    const int nblkNw4 = (N + 3) / 4;      // 256-thread, 4 nodes (gatherh1)
    const int nblkN16 = (N + 15) / 16;    // 256-thread, 16 nodes (aggh1f)
    const int gemmx  = (N + 63) / 64;
    const int EDGE_BLOCKS = 3072;         // divisible by 8 (XCD swizzle)
    const int nwaves = EDGE_BLOCKS * 4;

    // weight frag prep (depends only on inputs; run first)
    prep_w_k<<<5, 256, 0, stream>>>(W2s, W2n, Wnp, We1, Wl1,
                                    w2sF, w2nF, wnpF, wbigF, efragT);

    // CSR build: single atomic pass (rank) + scan + atomic-free fill
    hipMemsetAsync(deg, 0, (size_t)N * sizeof(int), stream);
    rank_k<<<nblkE, 256, 0, stream>>>(dst, deg, rank, E);
    scan1_k<<<nblkN1, 256, 0, stream>>>(deg, off, bsum, N);
    scan2_k<<<1, 512, 0, stream>>>(bsum, nblkN1);
    scan3_k<<<nblkN1, 256, 0, stream>>>(off, bsum, N, E);
    fill2_k<<<nblkE, 256, 0, stream>>>(src, dst, off, rank, slot4, E);

    // layer 1 (fused aggregate + h1, bf16 out; quarter-wave per node)
    aggh1f_k<<<nblkN16, 256, 0, stream>>>(off, slot4, nf, W1s, W1n, b1, h1b, N);

    // layer 2 gather (bf16 out, uint4, 16 rows in flight, index prefetch)
    gatherh1_k<<<nblkNw4, 256, 0, stream>>>(off, slot4, (const uint4*)h1b,
                                            (uint4*)ah1b, N);

    // fused node MLP on matrix cores -> bf16 ST table
    node_mlp_mfma_k<<<gemmx, 256, 0, stream>>>((const uint4*)h1b, (const uint4*)ah1b,
                                               w2sF, w2nF, wnpF, wbigF,
                                               b2, bnp, be1, ST, N);

    // per-edge scoring (MFMA ef-offload, XCD-chunked swizzle)
    edge_k<<<EDGE_BLOCKS, 256, 0, stream>>>(slot4, ef, (const unsigned*)ST,
                                            efragT, We2, be2, bl1, Wl2, bl2,
                                            out, E, nwaves);
}

// Round 13
// 445.872 us; speedup vs baseline: 1.0534x; 1.0170x over previous
//
#include <hip/hip_runtime.h>
#include <math.h>

// ---------------------------------------------------------------------------
// EdgeClassifier: 2x SAGEConv(mean) -> per-node MLP -> edge scorer
// FINAL CONFIG = R8 (session best, 449.3us). All levers adjudicated:
//  * edge_k is FETCH-bound at its random-gather achievable BW:
//    scalar-VALU (R4, 131us, VALU 86%) == MFMA (R8, 133us, VALU 57%) ==
//    deep-pipeline (R9, null, occ 20%) with FETCH invariant ~322MB.
//  * ef-prepack (R10/R11): edge -28us but tail +40us -> net loss. RETIRED.
//  * XCD block swizzle (R12): null (grid-stride loop already interleaves
//    slot ranges globally; FETCH -0.8%). RETIRED.
//  * Packed-f2 (R3/R5): spills under all register budgets. RETIRED.
//  * Atomic-claim fill (R6): 140us, WRITE 101MB. RETIRED.
// Structure:
//  * layer-1 agg: mean commutes with projection -> aggregate raw nf (4-dim),
//    fused with h1 compute; quarter-wave (16 lanes) per node, DPP all-reduce
//  * CSR: rank_k (atomic returning rank) + scan + atomic-free fill2_k
//    scatter into slot4 {src, eid, dst, 0}
//  * gatherh1/aggh1f: 1-deep slot-index prefetch
//  * node_mlp_mfma_k: MFMA (16x16x32 bf16) node MLP; weights pre-split
//    hi/lo bf16 (prep_w_k); swapped operands -> direct ushort4 ST stores
//  * edge_k: MFMA ef-offload, 16 edges/wave, 1-deep slot4+ef prefetch
// ---------------------------------------------------------------------------

typedef __attribute__((ext_vector_type(8))) short bf16x8;
typedef __attribute__((ext_vector_type(4))) float f32x4;

__device__ __forceinline__ float fast_tanh(float x) {
    x = fminf(fmaxf(x, -15.f), 15.f);
    float e2 = __expf(2.f * x);
    return (e2 - 1.f) * __builtin_amdgcn_rcpf(e2 + 1.f);
}
__device__ __forceinline__ float fast_sigmoid(float x) {
    x = fminf(fmaxf(x, -60.f), 60.f);
    return __builtin_amdgcn_rcpf(1.f + __expf(-x));
}
__device__ __forceinline__ unsigned short f2bf(float f) {   // RNE
    unsigned u = __float_as_uint(f);
    u = u + 0x7FFFu + ((u >> 16) & 1u);
    return (unsigned short)(u >> 16);
}
__device__ __forceinline__ unsigned pack2bf(float lo, float hi) {
    return ((unsigned)f2bf(hi) << 16) | (unsigned)f2bf(lo);
}
__device__ __forceinline__ float bflo(unsigned u) { return __uint_as_float(u << 16); }
__device__ __forceinline__ float bfhi(unsigned u) { return __uint_as_float(u & 0xFFFF0000u); }
__device__ __forceinline__ float bf2f(unsigned short h) {
    return __uint_as_float((unsigned)h << 16);
}

__device__ __forceinline__ f32x4 mfma16(uint4 a, uint4 b, f32x4 c) {
    return __builtin_amdgcn_mfma_f32_16x16x32_bf16(
        __builtin_bit_cast(bf16x8, a), __builtin_bit_cast(bf16x8, b), c, 0, 0, 0);
}

// 16-lane all-reduce sum, pure DPP (no LDS/DS); reduces within 16-lane rows
__device__ __forceinline__ float dpp_sum16(float x) {
    int t;
    t = __builtin_amdgcn_update_dpp(0, __float_as_int(x), 0xB1, 0xF, 0xF, true);  // quad_perm(1,0,3,2)
    x += __int_as_float(t);
    t = __builtin_amdgcn_update_dpp(0, __float_as_int(x), 0x4E, 0xF, 0xF, true);  // quad_perm(2,3,0,1)
    x += __int_as_float(t);
    t = __builtin_amdgcn_update_dpp(0, __float_as_int(x), 0x141, 0xF, 0xF, true); // row_half_mirror
    x += __int_as_float(t);
    t = __builtin_amdgcn_update_dpp(0, __float_as_int(x), 0x140, 0xF, 0xF, true); // row_mirror
    x += __int_as_float(t);
    return x;
}

// rank[e] = arrival index among edges sharing dst; deg accumulates counts
__global__ void rank_k(const int* __restrict__ dst, int* __restrict__ deg,
                       int* __restrict__ rank, int E) {
    int e = blockIdx.x * blockDim.x + threadIdx.x;
    if (e < E) rank[e] = atomicAdd(&deg[dst[e]], 1);
}

__global__ void scan1_k(const int* __restrict__ deg, int* __restrict__ off,
                        int* __restrict__ bsum, int N) {
    __shared__ int tmp[256];
    int i = blockIdx.x * 256 + threadIdx.x;
    int v = (i < N) ? deg[i] : 0;
    tmp[threadIdx.x] = v;
    __syncthreads();
#pragma unroll
    for (int s = 1; s < 256; s <<= 1) {
        int t = (threadIdx.x >= s) ? tmp[threadIdx.x - s] : 0;
        __syncthreads();
        tmp[threadIdx.x] += t;
        __syncthreads();
    }
    if (i < N) off[i] = tmp[threadIdx.x] - v;
    if (threadIdx.x == 255) bsum[blockIdx.x] = tmp[255];
}

__global__ void scan2_k(int* __restrict__ bsum, int nb) {
    __shared__ int tmp[512];
    int i = threadIdx.x;
    int v = (i < nb) ? bsum[i] : 0;
    tmp[i] = v;
    __syncthreads();
#pragma unroll
    for (int s = 1; s < 512; s <<= 1) {
        int t = (i >= s) ? tmp[i - s] : 0;
        __syncthreads();
        tmp[i] += t;
        __syncthreads();
    }
    if (i < nb) bsum[i] = tmp[i] - v;
}

__global__ void scan3_k(int* __restrict__ off, const int* __restrict__ bsum,
                        int N, int E) {
    int i = blockIdx.x * 256 + threadIdx.x;
    if (i < N) off[i] += bsum[blockIdx.x];
    if (i == 0) off[N] = E;
}

// atomic-free CSR fill: single 16B scatter per edge {src, eid, dst, 0}
__global__ void fill2_k(const int* __restrict__ src, const int* __restrict__ dst,
                        const int* __restrict__ off, const int* __restrict__ rank,
                        int4* __restrict__ slot4, int E) {
    int e = blockIdx.x * blockDim.x + threadIdx.x;
    if (e >= E) return;
    int d = dst[e];
    int pos = off[d] + rank[e];
    slot4[pos] = make_int4(src[e], e, d, 0);
}

// ---------------------------------------------------------------------------
// Weight prep (runs once): MFMA fragment-layout hi/lo bf16 copies, plus
// edge A-frag table efragT[8][64]: tiles 0..3 = We1 rows 128..132 (t path),
// tiles 4..7 = Wl1 rows 128..132 (u path). kq==0 lanes carry hi bf16 at
// k=0..4; kq==1 lanes carry lo residual at k=8..12 (hi/lo-in-K trick:
// B duplicates ef in both k ranges, one MFMA sums both products).
// ---------------------------------------------------------------------------
__global__ void prep_w_k(const float* __restrict__ W2s, const float* __restrict__ W2n,
                         const float* __restrict__ Wnp, const float* __restrict__ We1,
                         const float* __restrict__ Wl1, uint4* __restrict__ w2sF,
                         uint4* __restrict__ w2nF, uint4* __restrict__ wnpF,
                         uint4* __restrict__ wbigF, uint4* __restrict__ efragT) {
    const int b = blockIdx.x, t = threadIdx.x;
    if (b < 3) {
        const float* W = (b == 0) ? W2s : (b == 1) ? W2n : Wnp;
        uint4* out = (b == 0) ? w2sF : (b == 1) ? w2nF : wnpF;
        for (int u = t; u < 2 * 4 * 64; u += 256) {
            int l = u & 63, nt = (u >> 6) & 3, ks = u >> 8;
            int m = nt * 16 + (l & 15), kb = ks * 32 + (l >> 4) * 8;
            unsigned hi[4], lo[4];
#pragma unroll
            for (int jp = 0; jp < 4; ++jp) {
                float v0 = W[(kb + 2 * jp) * 64 + m];
                float v1 = W[(kb + 2 * jp + 1) * 64 + m];
                unsigned short h0 = f2bf(v0), h1 = f2bf(v1);
                unsigned short q0 = f2bf(v0 - bf2f(h0)), q1 = f2bf(v1 - bf2f(h1));
                hi[jp] = ((unsigned)h1 << 16) | h0;
                lo[jp] = ((unsigned)q1 << 16) | q0;
            }
            out[u * 2]     = make_uint4(hi[0], hi[1], hi[2], hi[3]);
            out[u * 2 + 1] = make_uint4(lo[0], lo[1], lo[2], lo[3]);
        }
    } else if (b == 3) {
        for (int u = t; u < 2 * 16 * 64; u += 256) {
            int l = u & 63, nt = (u >> 6) & 15, ks = u >> 10;
            int m = nt * 16 + (l & 15), kb = ks * 32 + (l >> 4) * 8;
            int half = m >> 7, cc = m & 127, jj = cc >> 1, p = cc & 1;
            const float* W = p ? Wl1 : We1;
            unsigned hi[4], lo[4];
#pragma unroll
            for (int jp = 0; jp < 4; ++jp) {
                float v0 = W[(half * 64 + kb + 2 * jp) * 64 + jj];
                float v1 = W[(half * 64 + kb + 2 * jp + 1) * 64 + jj];
                unsigned short h0 = f2bf(v0), h1 = f2bf(v1);
                unsigned short q0 = f2bf(v0 - bf2f(h0)), q1 = f2bf(v1 - bf2f(h1));
                hi[jp] = ((unsigned)h1 << 16) | h0;
                lo[jp] = ((unsigned)q1 << 16) | q0;
            }
            wbigF[u * 2]     = make_uint4(hi[0], hi[1], hi[2], hi[3]);
            wbigF[u * 2 + 1] = make_uint4(lo[0], lo[1], lo[2], lo[3]);
        }
    } else {
        for (int u = t; u < 8 * 64; u += 256) {
            int l = u & 63, tile = u >> 6;
            int kq = l >> 4, m16 = l & 15;
            const float* W = (tile < 4) ? We1 : Wl1;
            int c = (tile & 3) * 16 + m16;
            unsigned uu0 = 0u, uu1 = 0u, uu2 = 0u;
            if (kq < 2) {
                float v[5];
#pragma unroll
                for (int j = 0; j < 5; ++j) {
                    float wv = W[(128 + j) * 64 + c];
                    unsigned short h = f2bf(wv);
                    v[j] = (kq == 0) ? bf2f(h) : (wv - bf2f(h));
                }
                uu0 = pack2bf(v[0], v[1]);
                uu1 = pack2bf(v[2], v[3]);
                uu2 = pack2bf(v[4], 0.f);
            }
            efragT[tile * 64 + l] = make_uint4(uu0, uu1, uu2, 0u);
        }
    }
}

// quarter-wave (16 lanes) per node, 16 nodes/block: aggnf = mean of
// nf[neighbors] (stride-16 gather + DPP-16 all-reduce, 1-deep index
// prefetch), then lane q computes h1 cols 4q..4q+3, packed bf16.
__global__ __launch_bounds__(256, 8)
void aggh1f_k(const int* __restrict__ off, const int4* __restrict__ slot4,
              const float* __restrict__ nf,
              const float* __restrict__ W1s, const float* __restrict__ W1n,
              const float* __restrict__ b1, unsigned* __restrict__ h1b, int N) {
    int n = blockIdx.x * 16 + (threadIdx.x >> 4);
    if (n >= N) return;
    int q = threadIdx.x & 15;
    int s0 = off[n], s1 = off[n + 1];
    const float4* nf4 = (const float4*)nf;
    float4 a = {0.f, 0.f, 0.f, 0.f};
    int i = s0 + q;
    int nx = (i < s1) ? slot4[i].x : 0;
    for (; i < s1; ) {
        int cur = nx;
        int in = i + 16;
        if (in < s1) nx = slot4[in].x;       // prefetch next index
        float4 r = nf4[(unsigned)cur];
        a.x += r.x; a.y += r.y; a.z += r.z; a.w += r.w;
        i = in;
    }
    a.x = dpp_sum16(a.x);
    a.y = dpp_sum16(a.y);
    a.z = dpp_sum16(a.z);
    a.w = dpp_sum16(a.w);
    float invd = 1.f / fmaxf((float)(s1 - s0), 1.f);
    a.x *= invd; a.y *= invd; a.z *= invd; a.w *= invd;
    float4 r = nf4[(unsigned)n];
    const int j0 = q << 2;
    float4 acc = *(const float4*)&b1[j0];
#pragma unroll
    for (int k = 0; k < 4; ++k) {
        float rk = (k == 0) ? r.x : (k == 1) ? r.y : (k == 2) ? r.z : r.w;
        float ak = (k == 0) ? a.x : (k == 1) ? a.y : (k == 2) ? a.z : a.w;
        float4 ws = *(const float4*)&W1s[k * 64 + j0];
        float4 wn = *(const float4*)&W1n[k * 64 + j0];
        acc.x = fmaf(rk, ws.x, acc.x); acc.y = fmaf(rk, ws.y, acc.y);
        acc.z = fmaf(rk, ws.z, acc.z); acc.w = fmaf(rk, ws.w, acc.w);
        acc.x = fmaf(ak, wn.x, acc.x); acc.y = fmaf(ak, wn.y, acc.y);
        acc.z = fmaf(ak, wn.z, acc.z); acc.w = fmaf(ak, wn.w, acc.w);
    }
    uint2 pk;
    pk.x = pack2bf(fmaxf(acc.x, 0.f), fmaxf(acc.y, 0.f));
    pk.y = pack2bf(fmaxf(acc.z, 0.f), fmaxf(acc.w, 0.f));
    *(uint2*)&h1b[(unsigned)n * 32u + (q << 1)] = pk;
}

// one wave per node (4 nodes/block): aggh1b[n] = mean of bf16 h1 rows.
// 16 rows in flight; next iteration's slot indices prefetched.
__global__ __launch_bounds__(256, 8)
void gatherh1_k(const int* __restrict__ off, const int4* __restrict__ slot4,
                const uint4* __restrict__ h1b4, uint4* __restrict__ ah1b4, int N) {
    int n = blockIdx.x * 4 + (threadIdx.x >> 6);
    if (n >= N) return;
    int l = threadIdx.x & 63;
    int g = l >> 3, q = l & 7;
    int s0 = off[n], s1 = off[n + 1];
    float a0 = 0.f, a1 = 0.f, a2 = 0.f, a3 = 0.f;
    float a4 = 0.f, a5 = 0.f, a6 = 0.f, a7 = 0.f;
    int i = s0;
    int nA = 0, nB = 0;
    if (i + 16 <= s1) { nA = slot4[i + g].x; nB = slot4[i + 8 + g].x; }
    for (; i + 16 <= s1; ) {
        int cA = nA, cB = nB;
        int in = i + 16;
        if (in + 16 <= s1) {
            nA = slot4[in + g].x;
            nB = slot4[in + 8 + g].x;
        }
        uint4 v0 = h1b4[(unsigned)cA * 8u + q];
        uint4 v1 = h1b4[(unsigned)cB * 8u + q];
        a0 += bflo(v0.x) + bflo(v1.x); a1 += bfhi(v0.x) + bfhi(v1.x);
        a2 += bflo(v0.y) + bflo(v1.y); a3 += bfhi(v0.y) + bfhi(v1.y);
        a4 += bflo(v0.z) + bflo(v1.z); a5 += bfhi(v0.z) + bfhi(v1.z);
        a6 += bflo(v0.w) + bflo(v1.w); a7 += bfhi(v0.w) + bfhi(v1.w);
        i = in;
    }
    for (; i + 8 <= s1; i += 8) {
        int r = slot4[i + g].x;
        uint4 v = h1b4[(unsigned)r * 8u + q];
        a0 += bflo(v.x); a1 += bfhi(v.x);
        a2 += bflo(v.y); a3 += bfhi(v.y);
        a4 += bflo(v.z); a5 += bfhi(v.z);
        a6 += bflo(v.w); a7 += bfhi(v.w);
    }
    int rem = s1 - i;
    if (g < rem) {
        int r = slot4[i + g].x;
        uint4 v = h1b4[(unsigned)r * 8u + q];
        a0 += bflo(v.x); a1 += bfhi(v.x);
        a2 += bflo(v.y); a3 += bfhi(v.y);
        a4 += bflo(v.z); a5 += bfhi(v.z);
        a6 += bflo(v.w); a7 += bfhi(v.w);
    }
#pragma unroll
    for (int m = 8; m <= 32; m <<= 1) {
        a0 += __shfl_xor(a0, m); a1 += __shfl_xor(a1, m);
        a2 += __shfl_xor(a2, m); a3 += __shfl_xor(a3, m);
        a4 += __shfl_xor(a4, m); a5 += __shfl_xor(a5, m);
        a6 += __shfl_xor(a6, m); a7 += __shfl_xor(a7, m);
    }
    if (l < 8) {
        float invd = 1.f / fmaxf((float)(s1 - s0), 1.f);
        uint4 pk;
        pk.x = pack2bf(a0 * invd, a1 * invd);
        pk.y = pack2bf(a2 * invd, a3 * invd);
        pk.z = pack2bf(a4 * invd, a5 * invd);
        pk.w = pack2bf(a6 * invd, a7 * invd);
        ah1b4[(unsigned)n * 8u + q] = pk;
    }
}

// ---------------------------------------------------------------------------
// MFMA node MLP (unchanged; verified absmax-identical).
// ---------------------------------------------------------------------------
__global__ __launch_bounds__(256)
void node_mlp_mfma_k(const uint4* __restrict__ h1v, const uint4* __restrict__ ahv,
                     const uint4* __restrict__ w2sF, const uint4* __restrict__ w2nF,
                     const uint4* __restrict__ wnpF, const uint4* __restrict__ wbigF,
                     const float* __restrict__ b2, const float* __restrict__ bnp,
                     const float* __restrict__ be1, unsigned short* __restrict__ ST,
                     int N) {
    __shared__ __align__(16) unsigned short Ahi[64][72];
    __shared__ __align__(16) unsigned short Alo[64][72];
    const int t = threadIdx.x;
    const int w = t >> 6, l = t & 63;
    const int lr = l & 15, kq = l >> 4;
    const int m0 = blockIdx.x * 64;
    const int gr = m0 + w * 16 + lr;
    const bool inb = gr < N;
    const int prow = w * 16 + lr;
    const int cbq = kq * 4;

    const uint4 z4 = make_uint4(0u, 0u, 0u, 0u);

    uint4 x1[2], xa[2];
#pragma unroll
    for (int ks = 0; ks < 2; ++ks) {
        unsigned idx = (unsigned)gr * 8u + (unsigned)(ks * 4 + kq);
        x1[ks] = inb ? h1v[idx] : z4;
        xa[ks] = inb ? ahv[idx] : z4;
    }

    // ---- layer 2: h2 = relu(X1@W2s + Xa@W2n + b2) ----
    f32x4 acc[4];
#pragma unroll
    for (int nt = 0; nt < 4; ++nt) acc[nt] = (f32x4){0.f, 0.f, 0.f, 0.f};
#pragma unroll
    for (int ks = 0; ks < 2; ++ks)
#pragma unroll
        for (int nt = 0; nt < 4; ++nt) {
            int base = ((ks * 4 + nt) * 64 + l) * 2;
            acc[nt] = mfma16(w2sF[base],     x1[ks], acc[nt]);
            acc[nt] = mfma16(w2sF[base + 1], x1[ks], acc[nt]);
            acc[nt] = mfma16(w2nF[base],     xa[ks], acc[nt]);
            acc[nt] = mfma16(w2nF[base + 1], xa[ks], acc[nt]);
        }
#pragma unroll
    for (int nt = 0; nt < 4; ++nt) {
        float4 vb = *(const float4*)&b2[nt * 16 + cbq];
        float v0 = fmaxf(acc[nt][0] + vb.x, 0.f);
        float v1 = fmaxf(acc[nt][1] + vb.y, 0.f);
        float v2 = fmaxf(acc[nt][2] + vb.z, 0.f);
        float v3 = fmaxf(acc[nt][3] + vb.w, 0.f);
        unsigned short h0 = f2bf(v0), h1 = f2bf(v1), h2 = f2bf(v2), h3 = f2bf(v3);
        unsigned short q0 = f2bf(v0 - bf2f(h0)), q1 = f2bf(v1 - bf2f(h1));
        unsigned short q2 = f2bf(v2 - bf2f(h2)), q3 = f2bf(v3 - bf2f(h3));
        *(uint2*)&Ahi[prow][nt * 16 + cbq] =
            make_uint2(((unsigned)h1 << 16) | h0, ((unsigned)h3 << 16) | h2);
        *(uint2*)&Alo[prow][nt * 16 + cbq] =
            make_uint2(((unsigned)q1 << 16) | q0, ((unsigned)q3 << 16) | q2);
    }
    __syncthreads();

    uint4 ahi2[2], alo2[2];
#pragma unroll
    for (int ks = 0; ks < 2; ++ks) {
        ahi2[ks] = *(const uint4*)&Ahi[prow][ks * 32 + kq * 8];
        alo2[ks] = *(const uint4*)&Alo[prow][ks * 32 + kq * 8];
    }

    // ---- layer 3: hn = relu(h2@Wnp + bnp) ----
    f32x4 a3[4];
#pragma unroll
    for (int nt = 0; nt < 4; ++nt) a3[nt] = (f32x4){0.f, 0.f, 0.f, 0.f};
#pragma unroll
    for (int ks = 0; ks < 2; ++ks)
#pragma unroll
        for (int nt = 0; nt < 4; ++nt) {
            int base = ((ks * 4 + nt) * 64 + l) * 2;
            a3[nt] = mfma16(wnpF[base],     ahi2[ks], a3[nt]);
            a3[nt] = mfma16(wnpF[base + 1], ahi2[ks], a3[nt]);
            a3[nt] = mfma16(wnpF[base],     alo2[ks], a3[nt]);
        }
#pragma unroll
    for (int nt = 0; nt < 4; ++nt) {
        float4 vb = *(const float4*)&bnp[nt * 16 + cbq];
        float v0 = fmaxf(a3[nt][0] + vb.x, 0.f);
        float v1 = fmaxf(a3[nt][1] + vb.y, 0.f);
        float v2 = fmaxf(a3[nt][2] + vb.z, 0.f);
        float v3 = fmaxf(a3[nt][3] + vb.w, 0.f);
        unsigned short h0 = f2bf(v0), h1 = f2bf(v1), h2 = f2bf(v2), h3 = f2bf(v3);
        unsigned short q0 = f2bf(v0 - bf2f(h0)), q1 = f2bf(v1 - bf2f(h1));
        unsigned short q2 = f2bf(v2 - bf2f(h2)), q3 = f2bf(v3 - bf2f(h3));
        *(uint2*)&Ahi[prow][nt * 16 + cbq] =
            make_uint2(((unsigned)h1 << 16) | h0, ((unsigned)h3 << 16) | h2);
        *(uint2*)&Alo[prow][nt * 16 + cbq] =
            make_uint2(((unsigned)q1 << 16) | q0, ((unsigned)q3 << 16) | q2);
    }
    __syncthreads();

    uint4 bhi[2], blo[2];
#pragma unroll
    for (int ks = 0; ks < 2; ++ks) {
        bhi[ks] = *(const uint4*)&Ahi[prow][ks * 32 + kq * 8];
        blo[ks] = *(const uint4*)&Alo[prow][ks * 32 + kq * 8];
    }

    // ---- layer 4: ST = hn @ Wbig, 16 col-tiles, direct ushort4 stores ----
#pragma unroll
    for (int mtg = 0; mtg < 4; ++mtg) {
        f32x4 a4[4];
#pragma unroll
        for (int m4 = 0; m4 < 4; ++m4) a4[m4] = (f32x4){0.f, 0.f, 0.f, 0.f};
#pragma unroll
        for (int m4 = 0; m4 < 4; ++m4) {
            int mt = mtg * 4 + m4;
#pragma unroll
            for (int ks = 0; ks < 2; ++ks) {
                int base = ((ks * 16 + mt) * 64 + l) * 2;
                a4[m4] = mfma16(wbigF[base],     bhi[ks], a4[m4]);
                a4[m4] = mfma16(wbigF[base + 1], bhi[ks], a4[m4]);
                a4[m4] = mfma16(wbigF[base],     blo[ks], a4[m4]);
            }
        }
#pragma unroll
        for (int m4 = 0; m4 < 4; ++m4) {
            int mt = mtg * 4 + m4;
            int stcb = mt * 16 + cbq;
            float v0 = a4[m4][0], v1 = a4[m4][1], v2 = a4[m4][2], v3 = a4[m4][3];
            if (mt >= 8) {
                int jj0 = (mt - 8) * 8 + kq * 2;
                v0 += be1[jj0];
                v2 += be1[jj0 + 1];
            }
            ushort4 pk;
            pk.x = f2bf(v0); pk.y = f2bf(v1); pk.z = f2bf(v2); pk.w = f2bf(v3);
            if (inb) *(ushort4*)&ST[(unsigned)gr * 256u + (unsigned)stcb] = pk;
        }
    }
}

// ---------------------------------------------------------------------------
// Edge scorer (MFMA, R8-proven form): wave = 16 edges. lane&15 = edge,
// rg = lane>>4 owns output cols tt*16+rg*4..+3 (node_mlp D mapping).
// 8 MFMAs (hi/lo folded into K) replace the scalar KS chains; z/o reduced
// via shfl_xor(16/32); 1-deep slot4+ef prefetch; ST gathers issue before
// the MFMAs for overlap. NO launch_bounds beyond (256).
// ---------------------------------------------------------------------------
__global__ __launch_bounds__(256)
void edge_k(const int4* __restrict__ slot4, const float* __restrict__ ef,
            const unsigned* __restrict__ ST32, const uint4* __restrict__ efragT,
            const float* __restrict__ We2, const float* __restrict__ be2,
            const float* __restrict__ bl1, const float* __restrict__ Wl2,
            const float* __restrict__ bl2, float* __restrict__ out,
            int E, int nwaves) {
    const int l = threadIdx.x & 63;
    const int e4 = l & 15;               // edge within 16-edge group
    const int rg = l >> 4;               // row-group: cols tt*16 + rg*4 .. +3
    const int rg4 = rg << 2;
    const int wid = blockIdx.x * (blockDim.x >> 6) + (threadIdx.x >> 6);
    const int ng = (E + 15) >> 4;
    const float vbe2 = be2[0], vbl2 = bl2[0];
    const bool bzero = rg >= 2;          // B-frag zero for k >= 16
    const uint4 z4u = make_uint4(0u, 0u, 0u, 0u);
    const f32x4 zf = {0.f, 0.f, 0.f, 0.f};

    // prologue prefetch (group wid)
    int4 sv; uint4 bfr; bool act;
    {
        int s = wid * 16 + e4;
        act = (wid < ng) && (s < E);
        sv = slot4[act ? (unsigned)s : 0u];
        const float* ep = ef + (unsigned)sv.y * 5u;
        unsigned b0 = pack2bf(ep[0], ep[1]);
        unsigned b1 = pack2bf(ep[2], ep[3]);
        unsigned b2 = pack2bf(ep[4], 0.f);
        bfr = bzero ? z4u : make_uint4(b0, b1, b2, 0u);
    }

    for (int g = wid; g < ng; ) {
        int gn = g + nwaves;
        // prefetch next group's slot4 + ef->B-frag
        int4 svn; uint4 bfn; bool actn;
        {
            int s = gn * 16 + e4;
            actn = (gn < ng) && (s < E);
            svn = slot4[actn ? (unsigned)s : 0u];
            const float* ep = ef + (unsigned)svn.y * 5u;
            unsigned b0 = pack2bf(ep[0], ep[1]);
            unsigned b1 = pack2bf(ep[2], ep[3]);
            unsigned b2 = pack2bf(ep[4], 0.f);
            bfn = bzero ? z4u : make_uint4(b0, b1, b2, 0u);
        }

        // issue all 8 ST gathers (latency hides under MFMAs below)
        unsigned srb = (unsigned)sv.x * 128u + (unsigned)rg4;
        unsigned drb = (unsigned)sv.z * 128u + 64u + (unsigned)rg4;
        uint4 sw0 = *(const uint4*)&ST32[srb];
        uint4 sw1 = *(const uint4*)&ST32[srb + 16u];
        uint4 sw2 = *(const uint4*)&ST32[srb + 32u];
        uint4 sw3 = *(const uint4*)&ST32[srb + 48u];
        uint4 pw0 = *(const uint4*)&ST32[drb];
        uint4 pw1 = *(const uint4*)&ST32[drb + 16u];
        uint4 pw2 = *(const uint4*)&ST32[drb + 32u];
        uint4 pw3 = *(const uint4*)&ST32[drb + 48u];

        // 8 MFMAs: D[m=out-col][n=edge]; hi/lo compensated via K-folding
        f32x4 dt0 = mfma16(efragT[0 * 64 + l], bfr, zf);
        f32x4 dt1 = mfma16(efragT[1 * 64 + l], bfr, zf);
        f32x4 dt2 = mfma16(efragT[2 * 64 + l], bfr, zf);
        f32x4 dt3 = mfma16(efragT[3 * 64 + l], bfr, zf);
        f32x4 du0 = mfma16(efragT[4 * 64 + l], bfr, zf);
        f32x4 du1 = mfma16(efragT[5 * 64 + l], bfr, zf);
        f32x4 du2 = mfma16(efragT[6 * 64 + l], bfr, zf);
        f32x4 du3 = mfma16(efragT[7 * 64 + l], bfr, zf);

        // t path: z = sum_c tanh(t_c) * We2_c   (be1 pre-folded into pw lo)
        float z = 0.f;
#define TT(i, DT, SW, PW) { \
        float4 w2v = *(const float4*)&We2[(i) * 16 + rg4]; \
        z = fmaf(fast_tanh(DT[0] + bflo(SW.x) + bflo(PW.x)), w2v.x, z); \
        z = fmaf(fast_tanh(DT[1] + bflo(SW.y) + bflo(PW.y)), w2v.y, z); \
        z = fmaf(fast_tanh(DT[2] + bflo(SW.z) + bflo(PW.z)), w2v.z, z); \
        z = fmaf(fast_tanh(DT[3] + bflo(SW.w) + bflo(PW.w)), w2v.w, z); }
        TT(0, dt0, sw0, pw0)
        TT(1, dt1, sw1, pw1)
        TT(2, dt2, sw2, pw2)
        TT(3, dt3, sw3, pw3)
#undef TT
        z += __shfl_xor(z, 16);
        z += __shfl_xor(z, 32);
        float w = fast_sigmoid(z + vbe2);

        // u path: o = sum_c relu(w*u_c + bl1_c) * Wl2_c
        float o = 0.f;
#define UT(i, DU, SW, PW) { \
        float4 blv = *(const float4*)&bl1[(i) * 16 + rg4]; \
        float4 wlv = *(const float4*)&Wl2[(i) * 16 + rg4]; \
        o = fmaf(fmaxf(fmaf(w, DU[0] + bfhi(SW.x) + bfhi(PW.x), blv.x), 0.f), wlv.x, o); \
        o = fmaf(fmaxf(fmaf(w, DU[1] + bfhi(SW.y) + bfhi(PW.y), blv.y), 0.f), wlv.y, o); \
        o = fmaf(fmaxf(fmaf(w, DU[2] + bfhi(SW.z) + bfhi(PW.z), blv.z), 0.f), wlv.z, o); \
        o = fmaf(fmaxf(fmaf(w, DU[3] + bfhi(SW.w) + bfhi(PW.w), blv.w), 0.f), wlv.w, o); }
        UT(0, du0, sw0, pw0)
        UT(1, du1, sw1, pw1)
        UT(2, du2, sw2, pw2)
        UT(3, du3, sw3, pw3)
#undef UT
        o += __shfl_xor(o, 16);
        o += __shfl_xor(o, 32);
        if (rg == 0 && act) out[(unsigned)sv.y] = o + vbl2;

        sv = svn; bfr = bfn; act = actn;
        g = gn;
    }
}

extern "C" void kernel_launch(void* const* d_in, const int* in_sizes, int n_in,
                              void* d_out, int out_size, void* d_ws, size_t ws_size,
                              hipStream_t stream) {
    const float* nf  = (const float*)d_in[0];
    const float* ef  = (const float*)d_in[1];
    const int*   src = (const int*)d_in[2];
    const int*   dst = (const int*)d_in[3];
    const float* W1s = (const float*)d_in[4];
    const float* W1n = (const float*)d_in[5];
    const float* b1  = (const float*)d_in[6];
    const float* W2s = (const float*)d_in[7];
    const float* W2n = (const float*)d_in[8];
    const float* b2  = (const float*)d_in[9];
    const float* Wnp = (const float*)d_in[10];
    const float* bnp = (const float*)d_in[11];
    const float* We1 = (const float*)d_in[12];
    const float* be1 = (const float*)d_in[13];
    const float* We2 = (const float*)d_in[14];
    const float* be2 = (const float*)d_in[15];
    const float* Wl1 = (const float*)d_in[16];
    const float* bl1 = (const float*)d_in[17];
    const float* Wl2 = (const float*)d_in[18];
    const float* bl2 = (const float*)d_in[19];

    const int N = in_sizes[0] / 4;
    const int E = in_sizes[2];

    // ws layout (float units), peak ~273N + 31K floats ≈ 109.4 MB (R8-proven):
    //  ST(bf16): [0, 128N)           written by node_mlp_mfma, read by edge_k
    //  ah1b:     [128N, 160N)        packed bf16 aggh1 (uint[32N])
    //  wfrag:    [160N, 160N+30720)  MFMA weight frags 7680 uint4 (120KB)
    //  h1b:      [160N+30720, +32N)  packed bf16 h1 (uint[32N])
    //  slot4:    [192N+30720, +64N)  int4[E] {src, eid, dst, 0}
    //  rank:     [256N+30720, +16N)  int[E]
    //  deg:      [272N+30720, +N)    int[N]
    //  off:      deg+N, N+1          int[N+1]
    //  bsum:     off+N+1             int[512]
    float* wsf = (float*)d_ws;
    unsigned short* ST = (unsigned short*)wsf;
    unsigned* ah1b = (unsigned*)(wsf + (size_t)128 * N);
    uint4* w2sF   = (uint4*)(wsf + (size_t)160 * N);
    uint4* w2nF   = w2sF + 1024;
    uint4* wnpF   = w2sF + 2048;
    uint4* wbigF  = w2sF + 3072;
    uint4* efragT = w2sF + 7168;   // 512 uint4 -> ends at 7680 uint4
    unsigned* h1b  = (unsigned*)(wsf + (size_t)160 * N + 30720);
    int4* slot4 = (int4*)(wsf + (size_t)192 * N + 30720);
    int*  rank = (int*)(wsf + (size_t)256 * N + 30720);
    int*  deg  = (int*)(wsf + (size_t)272 * N + 30720);
    int*  off  = deg + N;
    int*  bsum = off + N + 1;
    float* out = (float*)d_out;

    const int nblkN1 = (N + 255) / 256;
    const int nblkE  = (E + 255) / 256;
    const int nblkNw4 = (N + 3) / 4;      // 256-thread, 4 nodes (gatherh1)
    const int nblkN16 = (N + 15) / 16;    // 256-thread, 16 nodes (aggh1f)
    const int gemmx  = (N + 63) / 64;
    const int EDGE_BLOCKS = 3072;
    const int nwaves = EDGE_BLOCKS * 4;

    // weight frag prep (depends only on inputs; run first)
    prep_w_k<<<5, 256, 0, stream>>>(W2s, W2n, Wnp, We1, Wl1,
                                    w2sF, w2nF, wnpF, wbigF, efragT);

    // CSR build: single atomic pass (rank) + scan + atomic-free fill
    hipMemsetAsync(deg, 0, (size_t)N * sizeof(int), stream);
    rank_k<<<nblkE, 256, 0, stream>>>(dst, deg, rank, E);
    scan1_k<<<nblkN1, 256, 0, stream>>>(deg, off, bsum, N);
    scan2_k<<<1, 512, 0, stream>>>(bsum, nblkN1);
    scan3_k<<<nblkN1, 256, 0, stream>>>(off, bsum, N, E);
    fill2_k<<<nblkE, 256, 0, stream>>>(src, dst, off, rank, slot4, E);

    // layer 1 (fused aggregate + h1, bf16 out; quarter-wave per node)
    aggh1f_k<<<nblkN16, 256, 0, stream>>>(off, slot4, nf, W1s, W1n, b1, h1b, N);

    // layer 2 gather (bf16 out, uint4, 16 rows in flight, index prefetch)
    gatherh1_k<<<nblkNw4, 256, 0, stream>>>(off, slot4, (const uint4*)h1b,
                                            (uint4*)ah1b, N);

    // fused node MLP on matrix cores -> bf16 ST table
    node_mlp_mfma_k<<<gemmx, 256, 0, stream>>>((const uint4*)h1b, (const uint4*)ah1b,
                                               w2sF, w2nF, wnpF, wbigF,
                                               b2, bnp, be1, ST, N);

    // per-edge scoring (MFMA ef-offload, 16 edges/wave, slot4 prefetch)
    edge_k<<<EDGE_BLOCKS, 256, 0, stream>>>(slot4, ef, (const unsigned*)ST,
                                            efragT, We2, be2, bl1, Wl2, bl2,
                                            out, E, nwaves);
}